// Round 9
// baseline (491.746 us; speedup 1.0000x reference)
//
#include <hip/hip_runtime.h>
#include <hip/hip_fp16.h>

constexpr int NN  = 50000;   // nodes
constexpr int NE  = 800000;  // edges
constexpr int CIN = 128;     // input channels
constexpr int CH  = 256;     // hidden channels
constexpr int NG  = 512;     // graphs

typedef unsigned short ushort_t;
typedef unsigned int uint_t;
typedef unsigned char uchar_t;
typedef __attribute__((ext_vector_type(2))) float f32x2_t;
typedef __attribute__((ext_vector_type(2))) uint_t u32x2_t;

static __device__ __forceinline__ ushort_t f2bf(float f) {
    uint_t u = __float_as_uint(f);
    u += 0x7fffu + ((u >> 16) & 1u);   // round-to-nearest-even
    return (ushort_t)(u >> 16);
}

static __device__ __forceinline__ float h16tof(uint_t bits) {
    return __half2float(__ushort_as_half((unsigned short)bits));
}

// ================= prep: fp32 -> bf16 converts =================
__global__ void conv_x_kernel(const float4* __restrict__ x, ushort4* __restrict__ xb, int n4) {
    int i = blockIdx.x * blockDim.x + threadIdx.x;
    if (i >= n4) return;
    float4 v = x[i];
    ushort4 o;
    o.x = f2bf(v.x); o.y = f2bf(v.y); o.z = f2bf(v.z); o.w = f2bf(v.w);
    xb[i] = o;
}

// all three weight transposes in one launch: Wt[n*K + k] = bf16(W[k*N + n])
__global__ void conv_wt3_kernel(const float* __restrict__ W0, const float* __restrict__ W1,
                                const float* __restrict__ W2, ushort_t* __restrict__ W0t,
                                ushort_t* __restrict__ W1t, ushort_t* __restrict__ W2t) {
    int i = blockIdx.x * blockDim.x + threadIdx.x;
    if (i < 32768) {                       // W0: [128,256]
        int k = i >> 8, n = i & 255;
        W0t[n * 128 + k] = f2bf(W0[i]);
    } else if (i < 98304) {                // W1: [256,256]
        int j = i - 32768;
        int k = j >> 8, n = j & 255;
        W1t[n * 256 + k] = f2bf(W1[j]);
    } else if (i < 163840) {               // W2: [256,256]
        int j = i - 98304;
        int k = j >> 8, n = j & 255;
        W2t[n * 256 + k] = f2bf(W2[j]);
    }
}

// ================= CSR build (8-aligned padded rows) =================
__global__ void count_kernel(const int* __restrict__ dst, int* __restrict__ cnt, int E) {
    int e = blockIdx.x * blockDim.x + threadIdx.x;
    if (e < E) atomicAdd(&cnt[dst[e]], 1);
}

__global__ __launch_bounds__(256) void scan_bsum_kernel(const int* __restrict__ cnt,
                                                        int* __restrict__ bsum, int n) {
    int i = blockIdx.x * 256 + threadIdx.x;
    int v = (i < n) ? ((cnt[i] + 7) & ~7) : 0;   // padded slot count
    #pragma unroll
    for (int off = 32; off >= 1; off >>= 1) v += __shfl_xor(v, off, 64);
    __shared__ int ws[4];
    if ((threadIdx.x & 63) == 0) ws[threadIdx.x >> 6] = v;
    __syncthreads();
    if (threadIdx.x == 0) bsum[blockIdx.x] = ws[0] + ws[1] + ws[2] + ws[3];
}

__global__ __launch_bounds__(256) void scan_boff_kernel(int* __restrict__ bsum, int nb) {
    int tid = threadIdx.x, lane = tid & 63, wid = tid >> 6;
    int v = (tid < nb) ? bsum[tid] : 0;
    int s = v;
    #pragma unroll
    for (int off = 1; off < 64; off <<= 1) {
        int t = __shfl_up(s, off, 64);
        if (lane >= off) s += t;
    }
    __shared__ int wsum[4];
    if (lane == 63) wsum[wid] = s;
    __syncthreads();
    int wadd = 0;
    #pragma unroll
    for (int w = 0; w < 4; w++) if (w < wid) wadd += wsum[w];
    if (tid < nb) bsum[tid] = wadd + s - v;   // exclusive
}

__global__ __launch_bounds__(256) void scan_final_kernel(const int* __restrict__ cnt,
                                                         const int* __restrict__ boff,
                                                         int* __restrict__ rowptr,
                                                         float* __restrict__ dinv, int n) {
    int tid = threadIdx.x, lane = tid & 63, wid = tid >> 6;
    int i = blockIdx.x * 256 + tid;
    int c = (i < n) ? cnt[i] : 0;
    int v = (c + 7) & ~7;                         // padded
    int s = v;
    #pragma unroll
    for (int off = 1; off < 64; off <<= 1) {
        int t = __shfl_up(s, off, 64);
        if (lane >= off) s += t;
    }
    __shared__ int wsum[4];
    if (lane == 63) wsum[wid] = s;
    __syncthreads();
    int wadd = boff[blockIdx.x];
    #pragma unroll
    for (int w = 0; w < 4; w++) if (w < wid) wadd += wsum[w];
    if (i < n) {
        rowptr[i] = wadd + s - v;
        dinv[i]   = rsqrtf((float)c + 1.0f);   // +1 self loop (real degree)
        if (i == n - 1) rowptr[n] = wadd + s;
    }
}

// scatter: write packed {src:16, f16(dinv[src]):16} per padded-CSR slot (4 B/edge).
__global__ void scatter_kernel(const int* __restrict__ src, const int* __restrict__ dst,
                               const int* __restrict__ rowptr, int* __restrict__ cursor,
                               const float* __restrict__ dinv, uint_t* __restrict__ epack, int E) {
    int e = blockIdx.x * blockDim.x + threadIdx.x;
    if (e >= E) return;
    int d = dst[e];
    int s = src[e];
    int p = rowptr[d] + atomicAdd(&cursor[d], 1);
    uint_t hb = (uint_t)__half_as_ushort(__float2half(dinv[s]));
    epack[p] = (uint_t)s | (hb << 16);
}

// ================= bf16 per-node gather aggregation (layer 0 only) ====
template <int C, int MODE>
__global__ __launch_bounds__(256) void node_agg_kernel(
    const ushort_t* __restrict__ h, const int* __restrict__ rowptr,
    const int* __restrict__ degc, const uint_t* __restrict__ epack,
    const float* __restrict__ dinv, const float* __restrict__ bias,
    const int* __restrict__ batch, void* __restrict__ out_v, int n) {
    constexpr int V = C / 64;                 // dwords (2 bf16) per lane per row
    int wave = threadIdx.x >> 6;
    int lane = threadIdx.x & 63;
    int d = blockIdx.x * 4 + wave;
    if (d >= n) return;

    int beg = __builtin_amdgcn_readfirstlane(rowptr[d]);
    int deg = __builtin_amdgcn_readfirstlane(degc[d]);
    const uint_t* hu = (const uint_t*)h;

    float acc[V] = {};
    const uint4* ep4 = (const uint4*)(epack + beg);   // 32 B aligned (beg % 8 == 0)
    uint4 ea, eb, na, nb;
    if (deg > 0) { ea = ep4[0]; eb = ep4[1]; }

    for (int e = 0; e < deg; e += 8) {
        int blk = e >> 3;
        if (e + 8 < deg) { na = ep4[blk * 2 + 2]; nb = ep4[blk * 2 + 3]; }
        uint_t eps[8] = {ea.x, ea.y, ea.z, ea.w, eb.x, eb.y, eb.z, eb.w};
        int   srcs[8];
        float wts[8];
        #pragma unroll
        for (int u = 0; u < 8; u++) {
            bool a = (e + u) < deg;           // wave-uniform
            srcs[u] = a ? (int)(eps[u] & 0xffffu) : d;
            wts[u]  = a ? h16tof(eps[u] >> 16) : 0.0f;
        }
        if constexpr (V == 4) {
            uint_t ra[8], rb[8];
            #pragma unroll
            for (int u = 0; u < 8; u++) {
                const uint_t* row = hu + (size_t)__builtin_amdgcn_readfirstlane(srcs[u]) * (C / 2);
                ra[u] = row[lane];
                rb[u] = row[64 + lane];
            }
            #pragma unroll
            for (int u = 0; u < 8; u++) {
                float w = wts[u];
                acc[0] += w * __uint_as_float(ra[u] << 16);
                acc[1] += w * __uint_as_float(ra[u] & 0xffff0000u);
                acc[2] += w * __uint_as_float(rb[u] << 16);
                acc[3] += w * __uint_as_float(rb[u] & 0xffff0000u);
            }
        } else {
            uint_t rv[8];
            #pragma unroll
            for (int u = 0; u < 8; u++) {
                const uint_t* row = hu + (size_t)__builtin_amdgcn_readfirstlane(srcs[u]) * (C / 2);
                rv[u] = row[lane];
            }
            #pragma unroll
            for (int u = 0; u < 8; u++) {
                float w = wts[u];
                acc[0] += w * __uint_as_float(rv[u] << 16);
                acc[1] += w * __uint_as_float(rv[u] & 0xffff0000u);
            }
        }
        ea = na; eb = nb;
    }

    float dd = dinv[d];
    float self[V];
    {
        const uint_t* row = hu + (size_t)d * (C / 2);
        uint_t sa = row[lane];
        self[0] = __uint_as_float(sa << 16);
        self[1] = __uint_as_float(sa & 0xffff0000u);
        if constexpr (V == 4) {
            uint_t sb = row[64 + lane];
            self[2] = __uint_as_float(sb << 16);
            self[3] = __uint_as_float(sb & 0xffff0000u);
        }
    }

    float r[V];
    if constexpr (MODE >= 1) {
        float2 bA = *(const float2*)(bias + 2 * lane);
        r[0] = fmaxf(dd * acc[0] + dd * dd * self[0] + bA.x, 0.0f);
        r[1] = fmaxf(dd * acc[1] + dd * dd * self[1] + bA.y, 0.0f);
        if constexpr (V == 4) {
            float2 bB = *(const float2*)(bias + 128 + 2 * lane);
            r[2] = fmaxf(dd * acc[2] + dd * dd * self[2] + bB.x, 0.0f);
            r[3] = fmaxf(dd * acc[3] + dd * dd * self[3] + bB.y, 0.0f);
        }
    } else {
        #pragma unroll
        for (int i = 0; i < V; i++)
            r[i] = dd * acc[i] + dd * dd * self[i];
    }

    if constexpr (MODE == 2) {
        float* o = (float*)out_v + (size_t)batch[d] * C;
        atomicAdd(o + 2 * lane, r[0]);
        atomicAdd(o + 2 * lane + 1, r[1]);
        if constexpr (V == 4) {
            atomicAdd(o + 128 + 2 * lane, r[2]);
            atomicAdd(o + 128 + 2 * lane + 1, r[3]);
        }
    } else {
        uint_t* o = (uint_t*)((ushort_t*)out_v + (size_t)d * C);
        __builtin_nontemporal_store((uint_t)f2bf(r[0]) | ((uint_t)f2bf(r[1]) << 16), &o[lane]);
        if constexpr (V == 4)
            __builtin_nontemporal_store((uint_t)f2bf(r[2]) | ((uint_t)f2bf(r[3]) << 16), &o[64 + lane]);
    }
}

// ============ fp8 per-node gather aggregation, SOFTWARE-PIPELINED ============
// READ1 layout: one 256 B dword load per row; lane owns channels 4l..4l+3.
// Double-buffered 8+8: epack prefetched TWO blocks ahead, gathers for block
// b+1 issued BEFORE consuming block b -> the vmcnt wait on block b's gathers
// permits block b+1's 8 gathers (+ epack) to stay in flight. Breaks the
// one-miss-latency-per-8-edges serialization of the old loop.
// No array deeper than 8 (R6's 16-arrays spilled to scratch: VGPR 36 + WRITE 2x).
// MODE 1: out bf16 = relu(dd*sum + dd^2*self + bias)
// MODE 2: atomicAdd relu(...) into fp32 out[batch[d]]
template <int MODE>
__global__ __launch_bounds__(256) void node_agg_fp8_kernel(
    const uchar_t* __restrict__ h8, const int* __restrict__ rowptr,
    const int* __restrict__ degc, const uint_t* __restrict__ epack,
    const float* __restrict__ dinv, const float* __restrict__ bias,
    const int* __restrict__ batch, void* __restrict__ out_v, int n) {
    int wave = threadIdx.x >> 6;
    int lane = threadIdx.x & 63;
    int d = blockIdx.x * 4 + wave;
    if (d >= n) return;

    int beg = __builtin_amdgcn_readfirstlane(rowptr[d]);
    int deg = __builtin_amdgcn_readfirstlane(degc[d]);
    const uint_t* hu = (const uint_t*)h8;     // row = 64 dwords (256 B)
    const uint4* ep4 = (const uint4*)(epack + beg);

    float a0 = 0.0f, a1 = 0.0f, a2 = 0.0f, a3 = 0.0f;
    int nblk = (deg + 7) >> 3;

    uint4 ec0, ec1;       // epack for current block (arrived)
    uint4 en0, en1;       // epack for next block
    uint_t rvC[8];        // gathers in flight: current block
    uint_t rvN[8];        // gathers in flight: next block

    if (nblk > 0) {
        ec0 = ep4[0]; ec1 = ep4[1];
        uint_t eps[8] = {ec0.x, ec0.y, ec0.z, ec0.w, ec1.x, ec1.y, ec1.z, ec1.w};
        #pragma unroll
        for (int u = 0; u < 8; u++) {
            int s = (u < deg) ? (int)(eps[u] & 0xffffu) : d;
            rvC[u] = hu[(size_t)__builtin_amdgcn_readfirstlane(s) * 64 + lane];
        }
        if (nblk > 1) { en0 = ep4[2]; en1 = ep4[3]; }
    }

    for (int b = 0; b < nblk; b++) {
        int e = b * 8;
        // prefetch epack two blocks ahead (sequential, L2-friendly)
        uint4 ef0, ef1;
        if (b + 2 < nblk) { ef0 = ep4[(b + 2) * 2]; ef1 = ep4[(b + 2) * 2 + 1]; }
        // issue gathers for block b+1 (addresses from en*, loaded last iteration)
        if (b + 1 < nblk) {
            uint_t eps[8] = {en0.x, en0.y, en0.z, en0.w, en1.x, en1.y, en1.z, en1.w};
            #pragma unroll
            for (int u = 0; u < 8; u++) {
                int s = (e + 8 + u < deg) ? (int)(eps[u] & 0xffffu) : d;
                rvN[u] = hu[(size_t)__builtin_amdgcn_readfirstlane(s) * 64 + lane];
            }
        }
        // consume current block (vmcnt wait allows rvN + ef to stay in flight)
        {
            uint_t eps[8] = {ec0.x, ec0.y, ec0.z, ec0.w, ec1.x, ec1.y, ec1.z, ec1.w};
            #pragma unroll
            for (int u = 0; u < 8; u++) {
                float w = (e + u < deg) ? h16tof(eps[u] >> 16) : 0.0f;
                f32x2_t lo = __builtin_amdgcn_cvt_pk_f32_fp8(rvC[u], false);
                f32x2_t hi = __builtin_amdgcn_cvt_pk_f32_fp8(rvC[u], true);
                a0 += w * lo.x;
                a1 += w * lo.y;
                a2 += w * hi.x;
                a3 += w * hi.y;
            }
        }
        // rotate buffers
        ec0 = en0; ec1 = en1; en0 = ef0; en1 = ef1;
        #pragma unroll
        for (int u = 0; u < 8; u++) rvC[u] = rvN[u];
    }

    float dd = dinv[d];
    float dd2 = dd * dd;
    uint_t sv = hu[(size_t)d * 64 + lane];
    f32x2_t slo = __builtin_amdgcn_cvt_pk_f32_fp8(sv, false);
    f32x2_t shi = __builtin_amdgcn_cvt_pk_f32_fp8(sv, true);

    float4 b4 = *(const float4*)(bias + 4 * lane);
    float r0 = fmaxf(dd * a0 + dd2 * slo.x + b4.x, 0.0f);
    float r1 = fmaxf(dd * a1 + dd2 * slo.y + b4.y, 0.0f);
    float r2 = fmaxf(dd * a2 + dd2 * shi.x + b4.z, 0.0f);
    float r3 = fmaxf(dd * a3 + dd2 * shi.y + b4.w, 0.0f);

    if constexpr (MODE == 2) {
        float* o = (float*)out_v + (size_t)batch[d] * CH + 4 * lane;
        atomicAdd(o + 0, r0);
        atomicAdd(o + 1, r1);
        atomicAdd(o + 2, r2);
        atomicAdd(o + 3, r3);
    } else {
        u32x2_t st;
        st.x = (uint_t)f2bf(r0) | ((uint_t)f2bf(r1) << 16);
        st.y = (uint_t)f2bf(r2) | ((uint_t)f2bf(r3) << 16);
        *((u32x2_t*)((ushort_t*)out_v + (size_t)d * CH) + lane) = st;
    }
}

// ================= bf16 MFMA GEMM: C[M,256] = A[M,K] @ Wt[N,K]^T =================
// F8OUT=1: stage fp8 e4m3 tile in LDS, copy out with uint4 stores (full sectors —
// byte-granular global stores caused write-allocate RMW storms in round 4).
typedef __attribute__((ext_vector_type(8))) short bf16x8;
typedef __attribute__((ext_vector_type(4))) float f32x4;

template <int MODE, int F8OUT>
__global__ __launch_bounds__(256) void gemm_bf16_kernel(
    const ushort_t* __restrict__ A, const ushort_t* __restrict__ Wt,
    const float* __restrict__ bias, void* __restrict__ Cv, int M, int K) {
    __shared__ union alignas(16) {
        ushort_t ab[2][128][40];
        uchar_t  f8[128][128];
    } smem;
    int tid = threadIdx.x;
    int row0 = blockIdx.x * 128, col0 = blockIdx.y * 128;
    int lr = tid >> 2, lq = tid & 3;
    int lane = tid & 63, wv = tid >> 6;
    int wr = (wv >> 1) * 64, wc = (wv & 1) * 64;
    int r16 = lane & 15, quad = lane >> 4;

    f32x4 acc[4][4] = {};

    for (int k0 = 0; k0 < K; k0 += 32) {
        {
            int gr0 = row0 + lr, gr1 = row0 + lr + 64;
            uint4 a0 = make_uint4(0, 0, 0, 0), a1 = make_uint4(0, 0, 0, 0);
            if (gr0 < M) a0 = *(const uint4*)(A + (size_t)gr0 * K + k0 + lq * 8);
            if (gr1 < M) a1 = *(const uint4*)(A + (size_t)gr1 * K + k0 + lq * 8);
            *(uint4*)&smem.ab[0][lr][lq * 8]      = a0;
            *(uint4*)&smem.ab[0][lr + 64][lq * 8] = a1;
            uint4 b0 = *(const uint4*)(Wt + (size_t)(col0 + lr) * K + k0 + lq * 8);
            uint4 b1 = *(const uint4*)(Wt + (size_t)(col0 + lr + 64) * K + k0 + lq * 8);
            *(uint4*)&smem.ab[1][lr][lq * 8]      = b0;
            *(uint4*)&smem.ab[1][lr + 64][lq * 8] = b1;
        }
        __syncthreads();
        bf16x8 af[4], bfr[4];
        #pragma unroll
        for (int i = 0; i < 4; i++) af[i]  = *(const bf16x8*)&smem.ab[0][wr + i * 16 + r16][quad * 8];
        #pragma unroll
        for (int j = 0; j < 4; j++) bfr[j] = *(const bf16x8*)&smem.ab[1][wc + j * 16 + r16][quad * 8];
        #pragma unroll
        for (int i = 0; i < 4; i++)
            #pragma unroll
            for (int j = 0; j < 4; j++)
                acc[i][j] = __builtin_amdgcn_mfma_f32_16x16x32_bf16(af[i], bfr[j], acc[i][j], 0, 0, 0);
        __syncthreads();
    }

    if constexpr (F8OUT) {
        // stage fp8 bytes in LDS (tile-local cols 0..127)
        #pragma unroll
        for (int j = 0; j < 4; j++) {
            int colt = wc + j * 16 + r16;
            #pragma unroll
            for (int i = 0; i < 4; i++) {
                #pragma unroll
                for (int r = 0; r < 4; r++) {
                    float v = acc[i][j][r];
                    uint_t pk = __builtin_amdgcn_cvt_pk_fp8_f32(v, v, 0u, false);
                    smem.f8[wr + i * 16 + quad * 4 + r][colt] = (uchar_t)(pk & 0xffu);
                }
            }
        }
        __syncthreads();
        // vectorized copy-out: 128 rows x 128 B, uint4 per thread x4
        uchar_t* C8 = (uchar_t*)Cv;
        #pragma unroll
        for (int k = 0; k < 4; k++) {
            int idx = k * 256 + tid;          // 0..1023
            int r = idx >> 3, coff = (idx & 7) * 16;
            if (row0 + r < M)
                *(uint4*)(C8 + (size_t)(row0 + r) * 256 + col0 + coff) =
                    *(const uint4*)&smem.f8[r][coff];
        }
    } else {
        #pragma unroll
        for (int j = 0; j < 4; j++) {
            int colc = col0 + wc + j * 16 + r16;
            float bval = (MODE == 1) ? bias[colc] : 0.0f;
            #pragma unroll
            for (int i = 0; i < 4; i++) {
                #pragma unroll
                for (int r = 0; r < 4; r++) {
                    int row = row0 + wr + i * 16 + quad * 4 + r;
                    if (row < M) {
                        float v = acc[i][j][r];
                        if (MODE == 1) v = fmaxf(v + bval, 0.0f);
                        ((ushort_t*)Cv)[(size_t)row * 256 + colc] = f2bf(v);
                    }
                }
            }
        }
    }
}

extern "C" void kernel_launch(void* const* d_in, const int* in_sizes, int n_in,
                              void* d_out, int out_size, void* d_ws, size_t ws_size,
                              hipStream_t stream) {
    const float* x   = (const float*)d_in[0];
    const float* W0  = (const float*)d_in[1];
    const float* b0  = (const float*)d_in[2];
    const float* W1  = (const float*)d_in[3];
    const float* b1  = (const float*)d_in[4];
    const float* W2  = (const float*)d_in[5];
    const float* b2  = (const float*)d_in[6];
    const int*   ei  = (const int*)d_in[7];
    const int*   src = ei;
    const int*   dst = ei + NE;
    const int*   batch = (const int*)d_in[8];
    float* out = (float*)d_out;

    char* ws = (char*)d_ws;
    ushort_t* P1  = (ushort_t*)ws;                        // [NN,256] bf16 (h1, then h2) 25.6 MB
    ushort_t* G0  = (ushort_t*)(ws + 25600000ull);        // [NN,128] bf16 (agg0 out)    12.8 MB
    uchar_t*  F8  = (uchar_t*) (ws + 38400000ull);        // [NN,256] fp8 (t1, then t2)  12.8 MB
    ushort_t* xbf = (ushort_t*)(ws + 51200000ull);        // [NN,128] bf16               12.8 MB
    ushort_t* W0t = (ushort_t*)(ws + 64000000ull);        // [256,128] bf16
    ushort_t* W1t = (ushort_t*)(ws + 64065536ull);        // [256,256] bf16
    ushort_t* W2t = (ushort_t*)(ws + 64196608ull);        // [256,256] bf16
    float*    dinv   = (float*)(ws + 64327680ull);        // [NN]
    int*      rowptr = (int*)  (ws + 64527680ull);        // [NN+1]
    int*      cnt    = (int*)  (ws + 64727808ull);        // [NN] real degrees (kept)
    uint_t*   epack  = (uint_t*)(ws + 64927808ull);       // padded CSR, <= 4.8 MB
    int*      bsum   = (int*)  (ws + 71327808ull);        // [<=256]
    int*      cursor = (int*)ws;                          // aliases P1 (free until GEMM0)

    const int scanBlocks = (NN + 255) / 256;              // 196
    const int nodeBlocks = (NN + 3) / 4;                  // 1 node per wave, 4 waves/block
    const dim3 ggrid((NN + 127) / 128, 2);

    // --- prep converts ---
    conv_x_kernel<<<(NN * CIN / 4 + 255) / 256, 256, 0, stream>>>((const float4*)x, (ushort4*)xbf, NN * CIN / 4);
    conv_wt3_kernel<<<640, 256, 0, stream>>>(W0, W1, W2, W0t, W1t, W2t);

    // --- CSR + normalization (8-aligned padded rows) ---
    hipMemsetAsync(cnt, 0, (size_t)NN * 4, stream);
    count_kernel<<<(NE + 255) / 256, 256, 0, stream>>>(dst, cnt, NE);
    scan_bsum_kernel<<<scanBlocks, 256, 0, stream>>>(cnt, bsum, NN);
    scan_boff_kernel<<<1, 256, 0, stream>>>(bsum, scanBlocks);
    scan_final_kernel<<<scanBlocks, 256, 0, stream>>>(cnt, bsum, rowptr, dinv, NN);
    hipMemsetAsync(cursor, 0, (size_t)NN * 4, stream);
    scatter_kernel<<<(NE + 255) / 256, 256, 0, stream>>>(src, dst, rowptr, cursor, dinv, epack, NE);

    // --- layer 0: agg x (bf16, C=128), GEMM0 fused bias+relu -> h1 (bf16) ---
    node_agg_kernel<CIN, 0><<<nodeBlocks, 256, 0, stream>>>(xbf, rowptr, cnt, epack, dinv, nullptr, nullptr, G0, NN);
    gemm_bf16_kernel<1, 0><<<ggrid, 256, 0, stream>>>(G0, W0t, b0, P1, NN, CIN);

    // --- layer 1: t1 = h1@W1 (fp8 out via LDS repack), agg fp8 pipelined -> h2 ---
    gemm_bf16_kernel<0, 1><<<ggrid, 256, 0, stream>>>(P1, W1t, nullptr, F8, NN, CH);
    node_agg_fp8_kernel<1><<<nodeBlocks, 256, 0, stream>>>(F8, rowptr, cnt, epack, dinv, b1, nullptr, P1, NN);

    // --- layer 2: t2 = h2@W2 (fp8 out via LDS repack), agg fp8 pipelined + pool ---
    gemm_bf16_kernel<0, 1><<<ggrid, 256, 0, stream>>>(P1, W2t, nullptr, F8, NN, CH);
    hipMemsetAsync(out, 0, (size_t)NG * CH * 4, stream);
    node_agg_fp8_kernel<2><<<nodeBlocks, 256, 0, stream>>>(F8, rowptr, cnt, epack, dinv, b2, batch, out, NN);
}

// Round 10
// 490.225 us; speedup vs baseline: 1.0031x; 1.0031x over previous
//
#include <hip/hip_runtime.h>
#include <hip/hip_fp16.h>

constexpr int NN  = 50000;   // nodes
constexpr int NE  = 800000;  // edges
constexpr int CIN = 128;     // input channels
constexpr int CH  = 256;     // hidden channels
constexpr int NG  = 512;     // graphs

typedef unsigned short ushort_t;
typedef unsigned int uint_t;
typedef unsigned char uchar_t;
typedef __attribute__((ext_vector_type(2))) float f32x2_t;
typedef __attribute__((ext_vector_type(2))) uint_t u32x2_t;

static __device__ __forceinline__ ushort_t f2bf(float f) {
    uint_t u = __float_as_uint(f);
    u += 0x7fffu + ((u >> 16) & 1u);   // round-to-nearest-even
    return (ushort_t)(u >> 16);
}

static __device__ __forceinline__ float h16tof(uint_t bits) {
    return __half2float(__ushort_as_half((unsigned short)bits));
}

// ================= prep: fp32 -> bf16 converts =================
__global__ void conv_x_kernel(const float4* __restrict__ x, ushort4* __restrict__ xb, int n4) {
    int i = blockIdx.x * blockDim.x + threadIdx.x;
    if (i >= n4) return;
    float4 v = x[i];
    ushort4 o;
    o.x = f2bf(v.x); o.y = f2bf(v.y); o.z = f2bf(v.z); o.w = f2bf(v.w);
    xb[i] = o;
}

// all three weight transposes in one launch: Wt[n*K + k] = bf16(W[k*N + n])
__global__ void conv_wt3_kernel(const float* __restrict__ W0, const float* __restrict__ W1,
                                const float* __restrict__ W2, ushort_t* __restrict__ W0t,
                                ushort_t* __restrict__ W1t, ushort_t* __restrict__ W2t) {
    int i = blockIdx.x * blockDim.x + threadIdx.x;
    if (i < 32768) {                       // W0: [128,256]
        int k = i >> 8, n = i & 255;
        W0t[n * 128 + k] = f2bf(W0[i]);
    } else if (i < 98304) {                // W1: [256,256]
        int j = i - 32768;
        int k = j >> 8, n = j & 255;
        W1t[n * 256 + k] = f2bf(W1[j]);
    } else if (i < 163840) {               // W2: [256,256]
        int j = i - 98304;
        int k = j >> 8, n = j & 255;
        W2t[n * 256 + k] = f2bf(W2[j]);
    }
}

// ================= CSR build (8-aligned padded rows) =================
__global__ void count_kernel(const int* __restrict__ dst, int* __restrict__ cnt, int E) {
    int e = blockIdx.x * blockDim.x + threadIdx.x;
    if (e < E) atomicAdd(&cnt[dst[e]], 1);
}

__global__ __launch_bounds__(256) void scan_bsum_kernel(const int* __restrict__ cnt,
                                                        int* __restrict__ bsum, int n) {
    int i = blockIdx.x * 256 + threadIdx.x;
    int v = (i < n) ? ((cnt[i] + 7) & ~7) : 0;   // padded slot count
    #pragma unroll
    for (int off = 32; off >= 1; off >>= 1) v += __shfl_xor(v, off, 64);
    __shared__ int ws[4];
    if ((threadIdx.x & 63) == 0) ws[threadIdx.x >> 6] = v;
    __syncthreads();
    if (threadIdx.x == 0) bsum[blockIdx.x] = ws[0] + ws[1] + ws[2] + ws[3];
}

__global__ __launch_bounds__(256) void scan_boff_kernel(int* __restrict__ bsum, int nb) {
    int tid = threadIdx.x, lane = tid & 63, wid = tid >> 6;
    int v = (tid < nb) ? bsum[tid] : 0;
    int s = v;
    #pragma unroll
    for (int off = 1; off < 64; off <<= 1) {
        int t = __shfl_up(s, off, 64);
        if (lane >= off) s += t;
    }
    __shared__ int wsum[4];
    if (lane == 63) wsum[wid] = s;
    __syncthreads();
    int wadd = 0;
    #pragma unroll
    for (int w = 0; w < 4; w++) if (w < wid) wadd += wsum[w];
    if (tid < nb) bsum[tid] = wadd + s - v;   // exclusive
}

__global__ __launch_bounds__(256) void scan_final_kernel(const int* __restrict__ cnt,
                                                         const int* __restrict__ boff,
                                                         int* __restrict__ rowptr,
                                                         float* __restrict__ dinv, int n) {
    int tid = threadIdx.x, lane = tid & 63, wid = tid >> 6;
    int i = blockIdx.x * 256 + tid;
    int c = (i < n) ? cnt[i] : 0;
    int v = (c + 7) & ~7;                         // padded
    int s = v;
    #pragma unroll
    for (int off = 1; off < 64; off <<= 1) {
        int t = __shfl_up(s, off, 64);
        if (lane >= off) s += t;
    }
    __shared__ int wsum[4];
    if (lane == 63) wsum[wid] = s;
    __syncthreads();
    int wadd = boff[blockIdx.x];
    #pragma unroll
    for (int w = 0; w < 4; w++) if (w < wid) wadd += wsum[w];
    if (i < n) {
        rowptr[i] = wadd + s - v;
        dinv[i]   = rsqrtf((float)c + 1.0f);   // +1 self loop (real degree)
        if (i == n - 1) rowptr[n] = wadd + s;
    }
}

// scatter: write packed {src:16, f16(dinv[src]):16} per padded-CSR slot (4 B/edge).
__global__ void scatter_kernel(const int* __restrict__ src, const int* __restrict__ dst,
                               const int* __restrict__ rowptr, int* __restrict__ cursor,
                               const float* __restrict__ dinv, uint_t* __restrict__ epack, int E) {
    int e = blockIdx.x * blockDim.x + threadIdx.x;
    if (e >= E) return;
    int d = dst[e];
    int s = src[e];
    int p = rowptr[d] + atomicAdd(&cursor[d], 1);
    uint_t hb = (uint_t)__half_as_ushort(__float2half(dinv[s]));
    epack[p] = (uint_t)s | (hb << 16);
}

// ================= bf16 per-node gather aggregation (layer 0 only) ====
template <int C, int MODE>
__global__ __launch_bounds__(256) void node_agg_kernel(
    const ushort_t* __restrict__ h, const int* __restrict__ rowptr,
    const int* __restrict__ degc, const uint_t* __restrict__ epack,
    const float* __restrict__ dinv, const float* __restrict__ bias,
    const int* __restrict__ batch, void* __restrict__ out_v, int n) {
    constexpr int V = C / 64;                 // dwords (2 bf16) per lane per row
    int wave = threadIdx.x >> 6;
    int lane = threadIdx.x & 63;
    int d = blockIdx.x * 4 + wave;
    if (d >= n) return;

    int beg = __builtin_amdgcn_readfirstlane(rowptr[d]);
    int deg = __builtin_amdgcn_readfirstlane(degc[d]);
    const uint_t* hu = (const uint_t*)h;

    float acc[V] = {};
    const uint4* ep4 = (const uint4*)(epack + beg);   // 32 B aligned (beg % 8 == 0)
    uint4 ea, eb, na, nb;
    if (deg > 0) { ea = ep4[0]; eb = ep4[1]; }

    for (int e = 0; e < deg; e += 8) {
        int blk = e >> 3;
        if (e + 8 < deg) { na = ep4[blk * 2 + 2]; nb = ep4[blk * 2 + 3]; }
        uint_t eps[8] = {ea.x, ea.y, ea.z, ea.w, eb.x, eb.y, eb.z, eb.w};
        int   srcs[8];
        float wts[8];
        #pragma unroll
        for (int u = 0; u < 8; u++) {
            bool a = (e + u) < deg;           // wave-uniform
            srcs[u] = a ? (int)(eps[u] & 0xffffu) : d;
            wts[u]  = a ? h16tof(eps[u] >> 16) : 0.0f;
        }
        if constexpr (V == 4) {
            uint_t ra[8], rb[8];
            #pragma unroll
            for (int u = 0; u < 8; u++) {
                const uint_t* row = hu + (size_t)__builtin_amdgcn_readfirstlane(srcs[u]) * (C / 2);
                ra[u] = row[lane];
                rb[u] = row[64 + lane];
            }
            #pragma unroll
            for (int u = 0; u < 8; u++) {
                float w = wts[u];
                acc[0] += w * __uint_as_float(ra[u] << 16);
                acc[1] += w * __uint_as_float(ra[u] & 0xffff0000u);
                acc[2] += w * __uint_as_float(rb[u] << 16);
                acc[3] += w * __uint_as_float(rb[u] & 0xffff0000u);
            }
        } else {
            uint_t rv[8];
            #pragma unroll
            for (int u = 0; u < 8; u++) {
                const uint_t* row = hu + (size_t)__builtin_amdgcn_readfirstlane(srcs[u]) * (C / 2);
                rv[u] = row[lane];
            }
            #pragma unroll
            for (int u = 0; u < 8; u++) {
                float w = wts[u];
                acc[0] += w * __uint_as_float(rv[u] << 16);
                acc[1] += w * __uint_as_float(rv[u] & 0xffff0000u);
            }
        }
        ea = na; eb = nb;
    }

    float dd = dinv[d];
    float self[V];
    {
        const uint_t* row = hu + (size_t)d * (C / 2);
        uint_t sa = row[lane];
        self[0] = __uint_as_float(sa << 16);
        self[1] = __uint_as_float(sa & 0xffff0000u);
        if constexpr (V == 4) {
            uint_t sb = row[64 + lane];
            self[2] = __uint_as_float(sb << 16);
            self[3] = __uint_as_float(sb & 0xffff0000u);
        }
    }

    float r[V];
    if constexpr (MODE >= 1) {
        float2 bA = *(const float2*)(bias + 2 * lane);
        r[0] = fmaxf(dd * acc[0] + dd * dd * self[0] + bA.x, 0.0f);
        r[1] = fmaxf(dd * acc[1] + dd * dd * self[1] + bA.y, 0.0f);
        if constexpr (V == 4) {
            float2 bB = *(const float2*)(bias + 128 + 2 * lane);
            r[2] = fmaxf(dd * acc[2] + dd * dd * self[2] + bB.x, 0.0f);
            r[3] = fmaxf(dd * acc[3] + dd * dd * self[3] + bB.y, 0.0f);
        }
    } else {
        #pragma unroll
        for (int i = 0; i < V; i++)
            r[i] = dd * acc[i] + dd * dd * self[i];
    }

    if constexpr (MODE == 2) {
        float* o = (float*)out_v + (size_t)batch[d] * C;
        atomicAdd(o + 2 * lane, r[0]);
        atomicAdd(o + 2 * lane + 1, r[1]);
        if constexpr (V == 4) {
            atomicAdd(o + 128 + 2 * lane, r[2]);
            atomicAdd(o + 128 + 2 * lane + 1, r[3]);
        }
    } else {
        uint_t* o = (uint_t*)((ushort_t*)out_v + (size_t)d * C);
        __builtin_nontemporal_store((uint_t)f2bf(r[0]) | ((uint_t)f2bf(r[1]) << 16), &o[lane]);
        if constexpr (V == 4)
            __builtin_nontemporal_store((uint_t)f2bf(r[2]) | ((uint_t)f2bf(r[3]) << 16), &o[64 + lane]);
    }
}

// ======== fp8 gather aggregation: TWO NODES PER WAVE (depth-16 MLP) ========
// Each wave owns nodes dA=2w, dB=2w+1 and runs two independent 8-edge streams
// per iteration: gathers for A issued, then B, then A consumed (its vmcnt wait
// leaves B's 8 gathers in flight), then B. 16 outstanding gathers steady-state,
// NO loop-carried arrays (R6/R9's rotation arrays spilled to scratch: the
// VGPR~36 + WRITE 2x + occupancy 60% fingerprint).
// READ1 layout: one 256 B dword load per row; lane owns channels 4l..4l+3.
// MODE 1: out bf16 = relu(dd*sum + dd^2*self + bias)
// MODE 2: atomicAdd relu(...) into fp32 out[batch[d]]
template <int MODE>
__global__ __launch_bounds__(256) void node_agg_fp8_kernel(
    const uchar_t* __restrict__ h8, const int* __restrict__ rowptr,
    const int* __restrict__ degc, const uint_t* __restrict__ epack,
    const float* __restrict__ dinv, const float* __restrict__ bias,
    const int* __restrict__ batch, void* __restrict__ out_v, int n) {
    int wave = threadIdx.x >> 6;
    int lane = threadIdx.x & 63;
    int dA = (blockIdx.x * 4 + wave) * 2;
    if (dA >= n) return;
    int dB = dA + 1;
    bool hasB = dB < n;
    if (!hasB) dB = dA;

    int begA = __builtin_amdgcn_readfirstlane(rowptr[dA]);
    int degA = __builtin_amdgcn_readfirstlane(degc[dA]);
    int begB = __builtin_amdgcn_readfirstlane(rowptr[dB]);
    int degB = hasB ? __builtin_amdgcn_readfirstlane(degc[dB]) : 0;

    const uint_t* hu = (const uint_t*)h8;       // row = 64 dwords (256 B)
    const uint4* epq = (const uint4*)epack;     // beg%8==0 -> beg/4 is even uint4 idx

    int nbA = (degA + 7) >> 3;
    int nbB = (degB + 7) >> 3;
    int nbMax = max(nbA, nbB);

    float aA0 = 0.0f, aA1 = 0.0f, aA2 = 0.0f, aA3 = 0.0f;
    float aB0 = 0.0f, aB1 = 0.0f, aB2 = 0.0f, aB3 = 0.0f;

    for (int b = 0; b < nbMax; b++) {
        int boA = min(b, max(nbA - 1, 0));      // clamp: off-end streams re-read
        int boB = min(b, max(nbB - 1, 0));      // their last block (w=0 anyway)
        uint4 eA0 = epq[(begA >> 2) + boA * 2];
        uint4 eA1 = epq[(begA >> 2) + boA * 2 + 1];
        uint4 eB0 = epq[(begB >> 2) + boB * 2];
        uint4 eB1 = epq[(begB >> 2) + boB * 2 + 1];

        uint_t epsA[8] = {eA0.x, eA0.y, eA0.z, eA0.w, eA1.x, eA1.y, eA1.z, eA1.w};
        uint_t epsB[8] = {eB0.x, eB0.y, eB0.z, eB0.w, eB1.x, eB1.y, eB1.z, eB1.w};
        float wA[8], wB[8];

        // issue 8 gathers for A
        uint_t rvA[8];
        #pragma unroll
        for (int u = 0; u < 8; u++) {
            bool act = (b * 8 + u) < degA;      // wave-uniform
            int s = act ? (int)(epsA[u] & 0xffffu) : dA;
            wA[u] = act ? h16tof(epsA[u] >> 16) : 0.0f;
            rvA[u] = hu[(size_t)__builtin_amdgcn_readfirstlane(s) * 64 + lane];
        }
        // issue 8 gathers for B (independent stream)
        uint_t rvB[8];
        #pragma unroll
        for (int u = 0; u < 8; u++) {
            bool act = (b * 8 + u) < degB;
            int s = act ? (int)(epsB[u] & 0xffffu) : dA;
            wB[u] = act ? h16tof(epsB[u] >> 16) : 0.0f;
            rvB[u] = hu[(size_t)__builtin_amdgcn_readfirstlane(s) * 64 + lane];
        }
        // consume A: vmcnt wait for rvA leaves rvB's 8 gathers in flight
        #pragma unroll
        for (int u = 0; u < 8; u++) {
            float w = wA[u];
            f32x2_t lo = __builtin_amdgcn_cvt_pk_f32_fp8(rvA[u], false);
            f32x2_t hi = __builtin_amdgcn_cvt_pk_f32_fp8(rvA[u], true);
            aA0 += w * lo.x;
            aA1 += w * lo.y;
            aA2 += w * hi.x;
            aA3 += w * hi.y;
        }
        // consume B
        #pragma unroll
        for (int u = 0; u < 8; u++) {
            float w = wB[u];
            f32x2_t lo = __builtin_amdgcn_cvt_pk_f32_fp8(rvB[u], false);
            f32x2_t hi = __builtin_amdgcn_cvt_pk_f32_fp8(rvB[u], true);
            aB0 += w * lo.x;
            aB1 += w * lo.y;
            aB2 += w * hi.x;
            aB3 += w * hi.y;
        }
    }

    float4 b4 = *(const float4*)(bias + 4 * lane);

    // epilogue node A
    {
        float dd = dinv[dA];
        float dd2 = dd * dd;
        uint_t sv = hu[(size_t)dA * 64 + lane];
        f32x2_t slo = __builtin_amdgcn_cvt_pk_f32_fp8(sv, false);
        f32x2_t shi = __builtin_amdgcn_cvt_pk_f32_fp8(sv, true);
        float r0 = fmaxf(dd * aA0 + dd2 * slo.x + b4.x, 0.0f);
        float r1 = fmaxf(dd * aA1 + dd2 * slo.y + b4.y, 0.0f);
        float r2 = fmaxf(dd * aA2 + dd2 * shi.x + b4.z, 0.0f);
        float r3 = fmaxf(dd * aA3 + dd2 * shi.y + b4.w, 0.0f);
        if constexpr (MODE == 2) {
            float* o = (float*)out_v + (size_t)batch[dA] * CH + 4 * lane;
            atomicAdd(o + 0, r0);
            atomicAdd(o + 1, r1);
            atomicAdd(o + 2, r2);
            atomicAdd(o + 3, r3);
        } else {
            u32x2_t st;
            st.x = (uint_t)f2bf(r0) | ((uint_t)f2bf(r1) << 16);
            st.y = (uint_t)f2bf(r2) | ((uint_t)f2bf(r3) << 16);
            *((u32x2_t*)((ushort_t*)out_v + (size_t)dA * CH) + lane) = st;
        }
    }
    // epilogue node B
    if (hasB) {
        float dd = dinv[dB];
        float dd2 = dd * dd;
        uint_t sv = hu[(size_t)dB * 64 + lane];
        f32x2_t slo = __builtin_amdgcn_cvt_pk_f32_fp8(sv, false);
        f32x2_t shi = __builtin_amdgcn_cvt_pk_f32_fp8(sv, true);
        float r0 = fmaxf(dd * aB0 + dd2 * slo.x + b4.x, 0.0f);
        float r1 = fmaxf(dd * aB1 + dd2 * slo.y + b4.y, 0.0f);
        float r2 = fmaxf(dd * aB2 + dd2 * shi.x + b4.z, 0.0f);
        float r3 = fmaxf(dd * aB3 + dd2 * shi.y + b4.w, 0.0f);
        if constexpr (MODE == 2) {
            float* o = (float*)out_v + (size_t)batch[dB] * CH + 4 * lane;
            atomicAdd(o + 0, r0);
            atomicAdd(o + 1, r1);
            atomicAdd(o + 2, r2);
            atomicAdd(o + 3, r3);
        } else {
            u32x2_t st;
            st.x = (uint_t)f2bf(r0) | ((uint_t)f2bf(r1) << 16);
            st.y = (uint_t)f2bf(r2) | ((uint_t)f2bf(r3) << 16);
            *((u32x2_t*)((ushort_t*)out_v + (size_t)dB * CH) + lane) = st;
        }
    }
}

// ================= bf16 MFMA GEMM: C[M,256] = A[M,K] @ Wt[N,K]^T =================
// F8OUT=1: stage fp8 e4m3 tile in LDS, copy out with uint4 stores (full sectors —
// byte-granular global stores caused write-allocate RMW storms in round 4).
typedef __attribute__((ext_vector_type(8))) short bf16x8;
typedef __attribute__((ext_vector_type(4))) float f32x4;

template <int MODE, int F8OUT>
__global__ __launch_bounds__(256) void gemm_bf16_kernel(
    const ushort_t* __restrict__ A, const ushort_t* __restrict__ Wt,
    const float* __restrict__ bias, void* __restrict__ Cv, int M, int K) {
    __shared__ union alignas(16) {
        ushort_t ab[2][128][40];
        uchar_t  f8[128][128];
    } smem;
    int tid = threadIdx.x;
    int row0 = blockIdx.x * 128, col0 = blockIdx.y * 128;
    int lr = tid >> 2, lq = tid & 3;
    int lane = tid & 63, wv = tid >> 6;
    int wr = (wv >> 1) * 64, wc = (wv & 1) * 64;
    int r16 = lane & 15, quad = lane >> 4;

    f32x4 acc[4][4] = {};

    for (int k0 = 0; k0 < K; k0 += 32) {
        {
            int gr0 = row0 + lr, gr1 = row0 + lr + 64;
            uint4 a0 = make_uint4(0, 0, 0, 0), a1 = make_uint4(0, 0, 0, 0);
            if (gr0 < M) a0 = *(const uint4*)(A + (size_t)gr0 * K + k0 + lq * 8);
            if (gr1 < M) a1 = *(const uint4*)(A + (size_t)gr1 * K + k0 + lq * 8);
            *(uint4*)&smem.ab[0][lr][lq * 8]      = a0;
            *(uint4*)&smem.ab[0][lr + 64][lq * 8] = a1;
            uint4 b0 = *(const uint4*)(Wt + (size_t)(col0 + lr) * K + k0 + lq * 8);
            uint4 b1 = *(const uint4*)(Wt + (size_t)(col0 + lr + 64) * K + k0 + lq * 8);
            *(uint4*)&smem.ab[1][lr][lq * 8]      = b0;
            *(uint4*)&smem.ab[1][lr + 64][lq * 8] = b1;
        }
        __syncthreads();
        bf16x8 af[4], bfr[4];
        #pragma unroll
        for (int i = 0; i < 4; i++) af[i]  = *(const bf16x8*)&smem.ab[0][wr + i * 16 + r16][quad * 8];
        #pragma unroll
        for (int j = 0; j < 4; j++) bfr[j] = *(const bf16x8*)&smem.ab[1][wc + j * 16 + r16][quad * 8];
        #pragma unroll
        for (int i = 0; i < 4; i++)
            #pragma unroll
            for (int j = 0; j < 4; j++)
                acc[i][j] = __builtin_amdgcn_mfma_f32_16x16x32_bf16(af[i], bfr[j], acc[i][j], 0, 0, 0);
        __syncthreads();
    }

    if constexpr (F8OUT) {
        // stage fp8 bytes in LDS (tile-local cols 0..127)
        #pragma unroll
        for (int j = 0; j < 4; j++) {
            int colt = wc + j * 16 + r16;
            #pragma unroll
            for (int i = 0; i < 4; i++) {
                #pragma unroll
                for (int r = 0; r < 4; r++) {
                    float v = acc[i][j][r];
                    uint_t pk = __builtin_amdgcn_cvt_pk_fp8_f32(v, v, 0u, false);
                    smem.f8[wr + i * 16 + quad * 4 + r][colt] = (uchar_t)(pk & 0xffu);
                }
            }
        }
        __syncthreads();
        // vectorized copy-out: 128 rows x 128 B, uint4 per thread x4
        uchar_t* C8 = (uchar_t*)Cv;
        #pragma unroll
        for (int k = 0; k < 4; k++) {
            int idx = k * 256 + tid;          // 0..1023
            int r = idx >> 3, coff = (idx & 7) * 16;
            if (row0 + r < M)
                *(uint4*)(C8 + (size_t)(row0 + r) * 256 + col0 + coff) =
                    *(const uint4*)&smem.f8[r][coff];
        }
    } else {
        #pragma unroll
        for (int j = 0; j < 4; j++) {
            int colc = col0 + wc + j * 16 + r16;
            float bval = (MODE == 1) ? bias[colc] : 0.0f;
            #pragma unroll
            for (int i = 0; i < 4; i++) {
                #pragma unroll
                for (int r = 0; r < 4; r++) {
                    int row = row0 + wr + i * 16 + quad * 4 + r;
                    if (row < M) {
                        float v = acc[i][j][r];
                        if (MODE == 1) v = fmaxf(v + bval, 0.0f);
                        ((ushort_t*)Cv)[(size_t)row * 256 + colc] = f2bf(v);
                    }
                }
            }
        }
    }
}

extern "C" void kernel_launch(void* const* d_in, const int* in_sizes, int n_in,
                              void* d_out, int out_size, void* d_ws, size_t ws_size,
                              hipStream_t stream) {
    const float* x   = (const float*)d_in[0];
    const float* W0  = (const float*)d_in[1];
    const float* b0  = (const float*)d_in[2];
    const float* W1  = (const float*)d_in[3];
    const float* b1  = (const float*)d_in[4];
    const float* W2  = (const float*)d_in[5];
    const float* b2  = (const float*)d_in[6];
    const int*   ei  = (const int*)d_in[7];
    const int*   src = ei;
    const int*   dst = ei + NE;
    const int*   batch = (const int*)d_in[8];
    float* out = (float*)d_out;

    char* ws = (char*)d_ws;
    ushort_t* P1  = (ushort_t*)ws;                        // [NN,256] bf16 (h1, then h2) 25.6 MB
    ushort_t* G0  = (ushort_t*)(ws + 25600000ull);        // [NN,128] bf16 (agg0 out)    12.8 MB
    uchar_t*  F8  = (uchar_t*) (ws + 38400000ull);        // [NN,256] fp8 (t1, then t2)  12.8 MB
    ushort_t* xbf = (ushort_t*)(ws + 51200000ull);        // [NN,128] bf16               12.8 MB
    ushort_t* W0t = (ushort_t*)(ws + 64000000ull);        // [256,128] bf16
    ushort_t* W1t = (ushort_t*)(ws + 64065536ull);        // [256,256] bf16
    ushort_t* W2t = (ushort_t*)(ws + 64196608ull);        // [256,256] bf16
    float*    dinv   = (float*)(ws + 64327680ull);        // [NN]
    int*      rowptr = (int*)  (ws + 64527680ull);        // [NN+1]
    int*      cnt    = (int*)  (ws + 64727808ull);        // [NN] real degrees (kept)
    uint_t*   epack  = (uint_t*)(ws + 64927808ull);       // padded CSR, <= 4.8 MB
    int*      bsum   = (int*)  (ws + 71327808ull);        // [<=256]
    int*      cursor = (int*)ws;                          // aliases P1 (free until GEMM0)

    const int scanBlocks = (NN + 255) / 256;              // 196
    const int nodeBlocks = (NN + 3) / 4;                  // 1 node per wave, 4 waves/block
    const int nodeBlocks2 = (NN + 7) / 8;                 // 2 nodes per wave, 4 waves/block
    const dim3 ggrid((NN + 127) / 128, 2);

    // --- prep converts ---
    conv_x_kernel<<<(NN * CIN / 4 + 255) / 256, 256, 0, stream>>>((const float4*)x, (ushort4*)xbf, NN * CIN / 4);
    conv_wt3_kernel<<<640, 256, 0, stream>>>(W0, W1, W2, W0t, W1t, W2t);

    // --- CSR + normalization (8-aligned padded rows) ---
    hipMemsetAsync(cnt, 0, (size_t)NN * 4, stream);
    count_kernel<<<(NE + 255) / 256, 256, 0, stream>>>(dst, cnt, NE);
    scan_bsum_kernel<<<scanBlocks, 256, 0, stream>>>(cnt, bsum, NN);
    scan_boff_kernel<<<1, 256, 0, stream>>>(bsum, scanBlocks);
    scan_final_kernel<<<scanBlocks, 256, 0, stream>>>(cnt, bsum, rowptr, dinv, NN);
    hipMemsetAsync(cursor, 0, (size_t)NN * 4, stream);
    scatter_kernel<<<(NE + 255) / 256, 256, 0, stream>>>(src, dst, rowptr, cursor, dinv, epack, NE);

    // --- layer 0: agg x (bf16, C=128), GEMM0 fused bias+relu -> h1 (bf16) ---
    node_agg_kernel<CIN, 0><<<nodeBlocks, 256, 0, stream>>>(xbf, rowptr, cnt, epack, dinv, nullptr, nullptr, G0, NN);
    gemm_bf16_kernel<1, 0><<<ggrid, 256, 0, stream>>>(G0, W0t, b0, P1, NN, CIN);

    // --- layer 1: t1 = h1@W1 (fp8 out via LDS repack), agg fp8 2-node -> h2 ---
    gemm_bf16_kernel<0, 1><<<ggrid, 256, 0, stream>>>(P1, W1t, nullptr, F8, NN, CH);
    node_agg_fp8_kernel<1><<<nodeBlocks2, 256, 0, stream>>>(F8, rowptr, cnt, epack, dinv, b1, nullptr, P1, NN);

    // --- layer 2: t2 = h2@W2 (fp8 out via LDS repack), agg fp8 2-node + pool ---
    gemm_bf16_kernel<0, 1><<<ggrid, 256, 0, stream>>>(P1, W2t, nullptr, F8, NN, CH);
    hipMemsetAsync(out, 0, (size_t)NG * CH * 4, stream);
    node_agg_fp8_kernel<2><<<nodeBlocks2, 256, 0, stream>>>(F8, rowptr, cnt, epack, dinv, b2, batch, out, NN);
}

// Round 11
// 487.816 us; speedup vs baseline: 1.0081x; 1.0049x over previous
//
#include <hip/hip_runtime.h>
#include <hip/hip_fp16.h>

constexpr int NN  = 50000;   // nodes
constexpr int NE  = 800000;  // edges
constexpr int CIN = 128;     // input channels
constexpr int CH  = 256;     // hidden channels
constexpr int NG  = 512;     // graphs

typedef unsigned short ushort_t;
typedef unsigned int uint_t;
typedef unsigned char uchar_t;
typedef __attribute__((ext_vector_type(2))) float f32x2_t;
typedef __attribute__((ext_vector_type(2))) uint_t u32x2_t;

static __device__ __forceinline__ ushort_t f2bf(float f) {
    uint_t u = __float_as_uint(f);
    u += 0x7fffu + ((u >> 16) & 1u);   // round-to-nearest-even
    return (ushort_t)(u >> 16);
}

static __device__ __forceinline__ float h16tof(uint_t bits) {
    return __half2float(__ushort_as_half((unsigned short)bits));
}

// ================= prep: fp32 -> bf16 converts =================
__global__ void conv_x_kernel(const float4* __restrict__ x, ushort4* __restrict__ xb, int n4) {
    int i = blockIdx.x * blockDim.x + threadIdx.x;
    if (i >= n4) return;
    float4 v = x[i];
    ushort4 o;
    o.x = f2bf(v.x); o.y = f2bf(v.y); o.z = f2bf(v.z); o.w = f2bf(v.w);
    xb[i] = o;
}

// all three weight transposes in one launch: Wt[n*K + k] = bf16(W[k*N + n])
__global__ void conv_wt3_kernel(const float* __restrict__ W0, const float* __restrict__ W1,
                                const float* __restrict__ W2, ushort_t* __restrict__ W0t,
                                ushort_t* __restrict__ W1t, ushort_t* __restrict__ W2t) {
    int i = blockIdx.x * blockDim.x + threadIdx.x;
    if (i < 32768) {                       // W0: [128,256]
        int k = i >> 8, n = i & 255;
        W0t[n * 128 + k] = f2bf(W0[i]);
    } else if (i < 98304) {                // W1: [256,256]
        int j = i - 32768;
        int k = j >> 8, n = j & 255;
        W1t[n * 256 + k] = f2bf(W1[j]);
    } else if (i < 163840) {               // W2: [256,256]
        int j = i - 98304;
        int k = j >> 8, n = j & 255;
        W2t[n * 256 + k] = f2bf(W2[j]);
    }
}

// ================= CSR build (16-aligned padded rows) =================
__global__ void count_kernel(const int* __restrict__ dst, int* __restrict__ cnt, int E) {
    int e = blockIdx.x * blockDim.x + threadIdx.x;
    if (e < E) atomicAdd(&cnt[dst[e]], 1);
}

__global__ __launch_bounds__(256) void scan_bsum_kernel(const int* __restrict__ cnt,
                                                        int* __restrict__ bsum, int n) {
    int i = blockIdx.x * 256 + threadIdx.x;
    int v = (i < n) ? ((cnt[i] + 15) & ~15) : 0;   // padded slot count
    #pragma unroll
    for (int off = 32; off >= 1; off >>= 1) v += __shfl_xor(v, off, 64);
    __shared__ int ws[4];
    if ((threadIdx.x & 63) == 0) ws[threadIdx.x >> 6] = v;
    __syncthreads();
    if (threadIdx.x == 0) bsum[blockIdx.x] = ws[0] + ws[1] + ws[2] + ws[3];
}

__global__ __launch_bounds__(256) void scan_boff_kernel(int* __restrict__ bsum, int nb) {
    int tid = threadIdx.x, lane = tid & 63, wid = tid >> 6;
    int v = (tid < nb) ? bsum[tid] : 0;
    int s = v;
    #pragma unroll
    for (int off = 1; off < 64; off <<= 1) {
        int t = __shfl_up(s, off, 64);
        if (lane >= off) s += t;
    }
    __shared__ int wsum[4];
    if (lane == 63) wsum[wid] = s;
    __syncthreads();
    int wadd = 0;
    #pragma unroll
    for (int w = 0; w < 4; w++) if (w < wid) wadd += wsum[w];
    if (tid < nb) bsum[tid] = wadd + s - v;   // exclusive
}

__global__ __launch_bounds__(256) void scan_final_kernel(const int* __restrict__ cnt,
                                                         const int* __restrict__ boff,
                                                         int* __restrict__ rowptr,
                                                         float* __restrict__ dinv, int n) {
    int tid = threadIdx.x, lane = tid & 63, wid = tid >> 6;
    int i = blockIdx.x * 256 + tid;
    int c = (i < n) ? cnt[i] : 0;
    int v = (c + 15) & ~15;                       // padded
    int s = v;
    #pragma unroll
    for (int off = 1; off < 64; off <<= 1) {
        int t = __shfl_up(s, off, 64);
        if (lane >= off) s += t;
    }
    __shared__ int wsum[4];
    if (lane == 63) wsum[wid] = s;
    __syncthreads();
    int wadd = boff[blockIdx.x];
    #pragma unroll
    for (int w = 0; w < 4; w++) if (w < wid) wadd += wsum[w];
    if (i < n) {
        rowptr[i] = wadd + s - v;
        dinv[i]   = rsqrtf((float)c + 1.0f);   // +1 self loop (real degree)
        if (i == n - 1) rowptr[n] = wadd + s;
    }
}

// scatter: write packed {src:16, f16(dinv[src]):16} per padded-CSR slot (4 B/edge).
__global__ void scatter_kernel(const int* __restrict__ src, const int* __restrict__ dst,
                               const int* __restrict__ rowptr, int* __restrict__ cursor,
                               const float* __restrict__ dinv, uint_t* __restrict__ epack, int E) {
    int e = blockIdx.x * blockDim.x + threadIdx.x;
    if (e >= E) return;
    int d = dst[e];
    int s = src[e];
    int p = rowptr[d] + atomicAdd(&cursor[d], 1);
    uint_t hb = (uint_t)__half_as_ushort(__float2half(dinv[s]));
    epack[p] = (uint_t)s | (hb << 16);
}

// ================= bf16 per-node gather aggregation (layer 0 only) ====
// 8-edge window (reads pad-16 epack safely: 16 | 8).
template <int C, int MODE>
__global__ __launch_bounds__(256) void node_agg_kernel(
    const ushort_t* __restrict__ h, const int* __restrict__ rowptr,
    const int* __restrict__ degc, const uint_t* __restrict__ epack,
    const float* __restrict__ dinv, const float* __restrict__ bias,
    const int* __restrict__ batch, void* __restrict__ out_v, int n) {
    constexpr int V = C / 64;                 // dwords (2 bf16) per lane per row
    int wave = threadIdx.x >> 6;
    int lane = threadIdx.x & 63;
    int d = blockIdx.x * 4 + wave;
    if (d >= n) return;

    int beg = __builtin_amdgcn_readfirstlane(rowptr[d]);
    int deg = __builtin_amdgcn_readfirstlane(degc[d]);
    const uint_t* hu = (const uint_t*)h;

    float acc[V] = {};
    const uint4* ep4 = (const uint4*)(epack + beg);   // 64 B aligned (beg % 16 == 0)
    uint4 ea, eb, na, nb;
    if (deg > 0) { ea = ep4[0]; eb = ep4[1]; }

    for (int e = 0; e < deg; e += 8) {
        int blk = e >> 3;
        if (e + 8 < deg) { na = ep4[blk * 2 + 2]; nb = ep4[blk * 2 + 3]; }
        uint_t eps[8] = {ea.x, ea.y, ea.z, ea.w, eb.x, eb.y, eb.z, eb.w};
        int   srcs[8];
        float wts[8];
        #pragma unroll
        for (int u = 0; u < 8; u++) {
            bool a = (e + u) < deg;           // wave-uniform
            srcs[u] = a ? (int)(eps[u] & 0xffffu) : d;
            wts[u]  = a ? h16tof(eps[u] >> 16) : 0.0f;
        }
        if constexpr (V == 4) {
            uint_t ra[8], rb[8];
            #pragma unroll
            for (int u = 0; u < 8; u++) {
                const uint_t* row = hu + (size_t)__builtin_amdgcn_readfirstlane(srcs[u]) * (C / 2);
                ra[u] = row[lane];
                rb[u] = row[64 + lane];
            }
            #pragma unroll
            for (int u = 0; u < 8; u++) {
                float w = wts[u];
                acc[0] += w * __uint_as_float(ra[u] << 16);
                acc[1] += w * __uint_as_float(ra[u] & 0xffff0000u);
                acc[2] += w * __uint_as_float(rb[u] << 16);
                acc[3] += w * __uint_as_float(rb[u] & 0xffff0000u);
            }
        } else {
            uint_t rv[8];
            #pragma unroll
            for (int u = 0; u < 8; u++) {
                const uint_t* row = hu + (size_t)__builtin_amdgcn_readfirstlane(srcs[u]) * (C / 2);
                rv[u] = row[lane];
            }
            #pragma unroll
            for (int u = 0; u < 8; u++) {
                float w = wts[u];
                acc[0] += w * __uint_as_float(rv[u] << 16);
                acc[1] += w * __uint_as_float(rv[u] & 0xffff0000u);
            }
        }
        ea = na; eb = nb;
    }

    float dd = dinv[d];
    float self[V];
    {
        const uint_t* row = hu + (size_t)d * (C / 2);
        uint_t sa = row[lane];
        self[0] = __uint_as_float(sa << 16);
        self[1] = __uint_as_float(sa & 0xffff0000u);
        if constexpr (V == 4) {
            uint_t sb = row[64 + lane];
            self[2] = __uint_as_float(sb << 16);
            self[3] = __uint_as_float(sb & 0xffff0000u);
        }
    }

    float r[V];
    if constexpr (MODE >= 1) {
        float2 bA = *(const float2*)(bias + 2 * lane);
        r[0] = fmaxf(dd * acc[0] + dd * dd * self[0] + bA.x, 0.0f);
        r[1] = fmaxf(dd * acc[1] + dd * dd * self[1] + bA.y, 0.0f);
        if constexpr (V == 4) {
            float2 bB = *(const float2*)(bias + 128 + 2 * lane);
            r[2] = fmaxf(dd * acc[2] + dd * dd * self[2] + bB.x, 0.0f);
            r[3] = fmaxf(dd * acc[3] + dd * dd * self[3] + bB.y, 0.0f);
        }
    } else {
        #pragma unroll
        for (int i = 0; i < V; i++)
            r[i] = dd * acc[i] + dd * dd * self[i];
    }

    if constexpr (MODE == 2) {
        float* o = (float*)out_v + (size_t)batch[d] * C;
        atomicAdd(o + 2 * lane, r[0]);
        atomicAdd(o + 2 * lane + 1, r[1]);
        if constexpr (V == 4) {
            atomicAdd(o + 128 + 2 * lane, r[2]);
            atomicAdd(o + 128 + 2 * lane + 1, r[3]);
        }
    } else {
        uint_t* o = (uint_t*)((ushort_t*)out_v + (size_t)d * C);
        __builtin_nontemporal_store((uint_t)f2bf(r[0]) | ((uint_t)f2bf(r[1]) << 16), &o[lane]);
        if constexpr (V == 4)
            __builtin_nontemporal_store((uint_t)f2bf(r[2]) | ((uint_t)f2bf(r[3]) << 16), &o[64 + lane]);
    }
}

// ====== fp8 gather aggregation: 16-edge window, REGISTER-BUDGETED ======
// One wave per node, 16 row-gathers in flight. __launch_bounds__(256, 4)
// grants ~128 VGPR/lane so the 16-deep arrays STAY IN REGISTERS — R6/R9/R10's
// identical attempts all scratch-spilled (VGPR 36 + WRITE 2x fingerprint)
// because the default occupancy heuristic capped the register budget.
// READ1 layout: one 256 B dword load/row, lane owns ch 4l..4l+3. Pad-16 CSR.
// MODE 1: out bf16 = relu(dd*sum + dd^2*self + bias)
// MODE 2: atomicAdd relu(...) into fp32 out[batch[d]]
template <int MODE>
__global__ __launch_bounds__(256, 4) void node_agg_fp8_kernel(
    const uchar_t* __restrict__ h8, const int* __restrict__ rowptr,
    const int* __restrict__ degc, const uint_t* __restrict__ epack,
    const float* __restrict__ dinv, const float* __restrict__ bias,
    const int* __restrict__ batch, void* __restrict__ out_v, int n) {
    int wave = threadIdx.x >> 6;
    int lane = threadIdx.x & 63;
    int d = blockIdx.x * 4 + wave;
    if (d >= n) return;

    int beg = __builtin_amdgcn_readfirstlane(rowptr[d]);
    int deg = __builtin_amdgcn_readfirstlane(degc[d]);
    const uint_t* hu = (const uint_t*)h8;     // row = 64 dwords (256 B)

    float a0 = 0.0f, a1 = 0.0f, a2 = 0.0f, a3 = 0.0f;
    const uint4* ep4 = (const uint4*)(epack + beg);   // 64 B aligned (beg % 16 == 0)
    uint4 e0, e1, e2, e3;
    if (deg > 0) { e0 = ep4[0]; e1 = ep4[1]; e2 = ep4[2]; e3 = ep4[3]; }
    uint4 n0 = e0, n1 = e1, n2 = e2, n3 = e3;

    for (int e = 0; e < deg; e += 16) {
        int blk = e >> 4;
        if (e + 16 < deg) {
            n0 = ep4[blk * 4 + 4]; n1 = ep4[blk * 4 + 5];
            n2 = ep4[blk * 4 + 6]; n3 = ep4[blk * 4 + 7];
        }
        uint_t eps[16] = {e0.x, e0.y, e0.z, e0.w, e1.x, e1.y, e1.z, e1.w,
                          e2.x, e2.y, e2.z, e2.w, e3.x, e3.y, e3.z, e3.w};
        int   srcs[16];
        float wts[16];
        #pragma unroll
        for (int u = 0; u < 16; u++) {
            bool a = (e + u) < deg;           // wave-uniform
            srcs[u] = a ? (int)(eps[u] & 0xffffu) : d;
            wts[u]  = a ? h16tof(eps[u] >> 16) : 0.0f;
        }
        uint_t rv[16];
        #pragma unroll
        for (int u = 0; u < 16; u++)
            rv[u] = hu[(size_t)__builtin_amdgcn_readfirstlane(srcs[u]) * 64 + lane];
        #pragma unroll
        for (int u = 0; u < 16; u++) {
            float w = wts[u];
            f32x2_t lo = __builtin_amdgcn_cvt_pk_f32_fp8(rv[u], false);
            f32x2_t hi = __builtin_amdgcn_cvt_pk_f32_fp8(rv[u], true);
            a0 += w * lo.x;
            a1 += w * lo.y;
            a2 += w * hi.x;
            a3 += w * hi.y;
        }
        e0 = n0; e1 = n1; e2 = n2; e3 = n3;
    }

    float dd = dinv[d];
    float dd2 = dd * dd;
    uint_t sv = hu[(size_t)d * 64 + lane];
    f32x2_t slo = __builtin_amdgcn_cvt_pk_f32_fp8(sv, false);
    f32x2_t shi = __builtin_amdgcn_cvt_pk_f32_fp8(sv, true);

    float4 b4 = *(const float4*)(bias + 4 * lane);
    float r0 = fmaxf(dd * a0 + dd2 * slo.x + b4.x, 0.0f);
    float r1 = fmaxf(dd * a1 + dd2 * slo.y + b4.y, 0.0f);
    float r2 = fmaxf(dd * a2 + dd2 * shi.x + b4.z, 0.0f);
    float r3 = fmaxf(dd * a3 + dd2 * shi.y + b4.w, 0.0f);

    if constexpr (MODE == 2) {
        float* o = (float*)out_v + (size_t)batch[d] * CH + 4 * lane;
        atomicAdd(o + 0, r0);
        atomicAdd(o + 1, r1);
        atomicAdd(o + 2, r2);
        atomicAdd(o + 3, r3);
    } else {
        u32x2_t st;
        st.x = (uint_t)f2bf(r0) | ((uint_t)f2bf(r1) << 16);
        st.y = (uint_t)f2bf(r2) | ((uint_t)f2bf(r3) << 16);
        *((u32x2_t*)((ushort_t*)out_v + (size_t)d * CH) + lane) = st;
    }
}

// ================= bf16 MFMA GEMM: C[M,256] = A[M,K] @ Wt[N,K]^T =================
// F8OUT=1: stage fp8 e4m3 tile in LDS, copy out with uint4 stores (full sectors —
// byte-granular global stores caused write-allocate RMW storms in round 4).
typedef __attribute__((ext_vector_type(8))) short bf16x8;
typedef __attribute__((ext_vector_type(4))) float f32x4;

template <int MODE, int F8OUT>
__global__ __launch_bounds__(256) void gemm_bf16_kernel(
    const ushort_t* __restrict__ A, const ushort_t* __restrict__ Wt,
    const float* __restrict__ bias, void* __restrict__ Cv, int M, int K) {
    __shared__ union alignas(16) {
        ushort_t ab[2][128][40];
        uchar_t  f8[128][128];
    } smem;
    int tid = threadIdx.x;
    int row0 = blockIdx.x * 128, col0 = blockIdx.y * 128;
    int lr = tid >> 2, lq = tid & 3;
    int lane = tid & 63, wv = tid >> 6;
    int wr = (wv >> 1) * 64, wc = (wv & 1) * 64;
    int r16 = lane & 15, quad = lane >> 4;

    f32x4 acc[4][4] = {};

    for (int k0 = 0; k0 < K; k0 += 32) {
        {
            int gr0 = row0 + lr, gr1 = row0 + lr + 64;
            uint4 a0 = make_uint4(0, 0, 0, 0), a1 = make_uint4(0, 0, 0, 0);
            if (gr0 < M) a0 = *(const uint4*)(A + (size_t)gr0 * K + k0 + lq * 8);
            if (gr1 < M) a1 = *(const uint4*)(A + (size_t)gr1 * K + k0 + lq * 8);
            *(uint4*)&smem.ab[0][lr][lq * 8]      = a0;
            *(uint4*)&smem.ab[0][lr + 64][lq * 8] = a1;
            uint4 b0 = *(const uint4*)(Wt + (size_t)(col0 + lr) * K + k0 + lq * 8);
            uint4 b1 = *(const uint4*)(Wt + (size_t)(col0 + lr + 64) * K + k0 + lq * 8);
            *(uint4*)&smem.ab[1][lr][lq * 8]      = b0;
            *(uint4*)&smem.ab[1][lr + 64][lq * 8] = b1;
        }
        __syncthreads();
        bf16x8 af[4], bfr[4];
        #pragma unroll
        for (int i = 0; i < 4; i++) af[i]  = *(const bf16x8*)&smem.ab[0][wr + i * 16 + r16][quad * 8];
        #pragma unroll
        for (int j = 0; j < 4; j++) bfr[j] = *(const bf16x8*)&smem.ab[1][wc + j * 16 + r16][quad * 8];
        #pragma unroll
        for (int i = 0; i < 4; i++)
            #pragma unroll
            for (int j = 0; j < 4; j++)
                acc[i][j] = __builtin_amdgcn_mfma_f32_16x16x32_bf16(af[i], bfr[j], acc[i][j], 0, 0, 0);
        __syncthreads();
    }

    if constexpr (F8OUT) {
        // stage fp8 bytes in LDS (tile-local cols 0..127)
        #pragma unroll
        for (int j = 0; j < 4; j++) {
            int colt = wc + j * 16 + r16;
            #pragma unroll
            for (int i = 0; i < 4; i++) {
                #pragma unroll
                for (int r = 0; r < 4; r++) {
                    float v = acc[i][j][r];
                    uint_t pk = __builtin_amdgcn_cvt_pk_fp8_f32(v, v, 0u, false);
                    smem.f8[wr + i * 16 + quad * 4 + r][colt] = (uchar_t)(pk & 0xffu);
                }
            }
        }
        __syncthreads();
        // vectorized copy-out: 128 rows x 128 B, uint4 per thread x4
        uchar_t* C8 = (uchar_t*)Cv;
        #pragma unroll
        for (int k = 0; k < 4; k++) {
            int idx = k * 256 + tid;          // 0..1023
            int r = idx >> 3, coff = (idx & 7) * 16;
            if (row0 + r < M)
                *(uint4*)(C8 + (size_t)(row0 + r) * 256 + col0 + coff) =
                    *(const uint4*)&smem.f8[r][coff];
        }
    } else {
        #pragma unroll
        for (int j = 0; j < 4; j++) {
            int colc = col0 + wc + j * 16 + r16;
            float bval = (MODE == 1) ? bias[colc] : 0.0f;
            #pragma unroll
            for (int i = 0; i < 4; i++) {
                #pragma unroll
                for (int r = 0; r < 4; r++) {
                    int row = row0 + wr + i * 16 + quad * 4 + r;
                    if (row < M) {
                        float v = acc[i][j][r];
                        if (MODE == 1) v = fmaxf(v + bval, 0.0f);
                        ((ushort_t*)Cv)[(size_t)row * 256 + colc] = f2bf(v);
                    }
                }
            }
        }
    }
}

extern "C" void kernel_launch(void* const* d_in, const int* in_sizes, int n_in,
                              void* d_out, int out_size, void* d_ws, size_t ws_size,
                              hipStream_t stream) {
    const float* x   = (const float*)d_in[0];
    const float* W0  = (const float*)d_in[1];
    const float* b0  = (const float*)d_in[2];
    const float* W1  = (const float*)d_in[3];
    const float* b1  = (const float*)d_in[4];
    const float* W2  = (const float*)d_in[5];
    const float* b2  = (const float*)d_in[6];
    const int*   ei  = (const int*)d_in[7];
    const int*   src = ei;
    const int*   dst = ei + NE;
    const int*   batch = (const int*)d_in[8];
    float* out = (float*)d_out;

    char* ws = (char*)d_ws;
    ushort_t* P1  = (ushort_t*)ws;                        // [NN,256] bf16 (h1, then h2) 25.6 MB
    ushort_t* G0  = (ushort_t*)(ws + 25600000ull);        // [NN,128] bf16 (agg0 out)    12.8 MB
    uchar_t*  F8  = (uchar_t*) (ws + 38400000ull);        // [NN,256] fp8 (t1, then t2)  12.8 MB
    ushort_t* xbf = (ushort_t*)(ws + 51200000ull);        // [NN,128] bf16               12.8 MB
    ushort_t* W0t = (ushort_t*)(ws + 64000000ull);        // [256,128] bf16
    ushort_t* W1t = (ushort_t*)(ws + 64065536ull);        // [256,256] bf16
    ushort_t* W2t = (ushort_t*)(ws + 64196608ull);        // [256,256] bf16
    float*    dinv   = (float*)(ws + 64327680ull);        // [NN]
    int*      rowptr = (int*)  (ws + 64527680ull);        // [NN+1]
    int*      cnt    = (int*)  (ws + 64727808ull);        // [NN] real degrees (kept)
    uint_t*   epack  = (uint_t*)(ws + 64927808ull);       // padded CSR (pad-16), <= 6.2 MB
    int*      bsum   = (int*)  (ws + 71327808ull);        // [<=256]
    int*      cursor = (int*)ws;                          // aliases P1 (free until GEMM0)

    const int scanBlocks = (NN + 255) / 256;              // 196
    const int nodeBlocks = (NN + 3) / 4;                  // 1 node per wave, 4 waves/block
    const dim3 ggrid((NN + 127) / 128, 2);

    // --- prep converts ---
    conv_x_kernel<<<(NN * CIN / 4 + 255) / 256, 256, 0, stream>>>((const float4*)x, (ushort4*)xbf, NN * CIN / 4);
    conv_wt3_kernel<<<640, 256, 0, stream>>>(W0, W1, W2, W0t, W1t, W2t);

    // --- CSR + normalization (16-aligned padded rows) ---
    hipMemsetAsync(cnt, 0, (size_t)NN * 4, stream);
    count_kernel<<<(NE + 255) / 256, 256, 0, stream>>>(dst, cnt, NE);
    scan_bsum_kernel<<<scanBlocks, 256, 0, stream>>>(cnt, bsum, NN);
    scan_boff_kernel<<<1, 256, 0, stream>>>(bsum, scanBlocks);
    scan_final_kernel<<<scanBlocks, 256, 0, stream>>>(cnt, bsum, rowptr, dinv, NN);
    hipMemsetAsync(cursor, 0, (size_t)NN * 4, stream);
    scatter_kernel<<<(NE + 255) / 256, 256, 0, stream>>>(src, dst, rowptr, cursor, dinv, epack, NE);

    // --- layer 0: agg x (bf16, C=128, 8-win), GEMM0 fused bias+relu -> h1 (bf16) ---
    node_agg_kernel<CIN, 0><<<nodeBlocks, 256, 0, stream>>>(xbf, rowptr, cnt, epack, dinv, nullptr, nullptr, G0, NN);
    gemm_bf16_kernel<1, 0><<<ggrid, 256, 0, stream>>>(G0, W0t, b0, P1, NN, CIN);

    // --- layer 1: t1 = h1@W1 (fp8 out via LDS repack), agg fp8 16-win -> h2 ---
    gemm_bf16_kernel<0, 1><<<ggrid, 256, 0, stream>>>(P1, W1t, nullptr, F8, NN, CH);
    node_agg_fp8_kernel<1><<<nodeBlocks, 256, 0, stream>>>(F8, rowptr, cnt, epack, dinv, b1, nullptr, P1, NN);

    // --- layer 2: t2 = h2@W2 (fp8 out via LDS repack), agg fp8 16-win + pool ---
    gemm_bf16_kernel<0, 1><<<ggrid, 256, 0, stream>>>(P1, W2t, nullptr, F8, NN, CH);
    hipMemsetAsync(out, 0, (size_t)NG * CH * 4, stream);
    node_agg_fp8_kernel<2><<<nodeBlocks, 256, 0, stream>>>(F8, rowptr, cnt, epack, dinv, b2, batch, out, NN);
}

// Round 12
// 395.752 us; speedup vs baseline: 1.2426x; 1.2326x over previous
//
#include <hip/hip_runtime.h>
#include <hip/hip_fp16.h>

constexpr int NN  = 50000;   // nodes
constexpr int NE  = 800000;  // edges
constexpr int CIN = 128;     // input channels
constexpr int CH  = 256;     // hidden channels
constexpr int NG  = 512;     // graphs

typedef unsigned short ushort_t;
typedef unsigned int uint_t;
typedef unsigned char uchar_t;
typedef __attribute__((ext_vector_type(2))) float f32x2_t;
typedef __attribute__((ext_vector_type(2))) uint_t u32x2_t;

static __device__ __forceinline__ ushort_t f2bf(float f) {
    uint_t u = __float_as_uint(f);
    u += 0x7fffu + ((u >> 16) & 1u);   // round-to-nearest-even
    return (ushort_t)(u >> 16);
}

static __device__ __forceinline__ float h16tof(uint_t bits) {
    return __half2float(__ushort_as_half((unsigned short)bits));
}

// ================= prep: fp32 -> bf16 converts =================
__global__ void conv_x_kernel(const float4* __restrict__ x, ushort4* __restrict__ xb, int n4) {
    int i = blockIdx.x * blockDim.x + threadIdx.x;
    if (i >= n4) return;
    float4 v = x[i];
    ushort4 o;
    o.x = f2bf(v.x); o.y = f2bf(v.y); o.z = f2bf(v.z); o.w = f2bf(v.w);
    xb[i] = o;
}

// all three weight transposes in one launch: Wt[n*K + k] = bf16(W[k*N + n])
__global__ void conv_wt3_kernel(const float* __restrict__ W0, const float* __restrict__ W1,
                                const float* __restrict__ W2, ushort_t* __restrict__ W0t,
                                ushort_t* __restrict__ W1t, ushort_t* __restrict__ W2t) {
    int i = blockIdx.x * blockDim.x + threadIdx.x;
    if (i < 32768) {                       // W0: [128,256]
        int k = i >> 8, n = i & 255;
        W0t[n * 128 + k] = f2bf(W0[i]);
    } else if (i < 98304) {                // W1: [256,256]
        int j = i - 32768;
        int k = j >> 8, n = j & 255;
        W1t[n * 256 + k] = f2bf(W1[j]);
    } else if (i < 163840) {               // W2: [256,256]
        int j = i - 98304;
        int k = j >> 8, n = j & 255;
        W2t[n * 256 + k] = f2bf(W2[j]);
    }
}

// ================= CSR build (8-aligned padded rows) =================
__global__ void count_kernel(const int* __restrict__ dst, int* __restrict__ cnt, int E) {
    int e = blockIdx.x * blockDim.x + threadIdx.x;
    if (e < E) atomicAdd(&cnt[dst[e]], 1);
}

__global__ __launch_bounds__(256) void scan_bsum_kernel(const int* __restrict__ cnt,
                                                        int* __restrict__ bsum, int n) {
    int i = blockIdx.x * 256 + threadIdx.x;
    int v = (i < n) ? ((cnt[i] + 7) & ~7) : 0;   // padded slot count
    #pragma unroll
    for (int off = 32; off >= 1; off >>= 1) v += __shfl_xor(v, off, 64);
    __shared__ int ws[4];
    if ((threadIdx.x & 63) == 0) ws[threadIdx.x >> 6] = v;
    __syncthreads();
    if (threadIdx.x == 0) bsum[blockIdx.x] = ws[0] + ws[1] + ws[2] + ws[3];
}

__global__ __launch_bounds__(256) void scan_boff_kernel(int* __restrict__ bsum, int nb) {
    int tid = threadIdx.x, lane = tid & 63, wid = tid >> 6;
    int v = (tid < nb) ? bsum[tid] : 0;
    int s = v;
    #pragma unroll
    for (int off = 1; off < 64; off <<= 1) {
        int t = __shfl_up(s, off, 64);
        if (lane >= off) s += t;
    }
    __shared__ int wsum[4];
    if (lane == 63) wsum[wid] = s;
    __syncthreads();
    int wadd = 0;
    #pragma unroll
    for (int w = 0; w < 4; w++) if (w < wid) wadd += wsum[w];
    if (tid < nb) bsum[tid] = wadd + s - v;   // exclusive
}

__global__ __launch_bounds__(256) void scan_final_kernel(const int* __restrict__ cnt,
                                                         const int* __restrict__ boff,
                                                         int* __restrict__ rowptr,
                                                         float* __restrict__ dinv, int n) {
    int tid = threadIdx.x, lane = tid & 63, wid = tid >> 6;
    int i = blockIdx.x * 256 + tid;
    int c = (i < n) ? cnt[i] : 0;
    int v = (c + 7) & ~7;                         // padded
    int s = v;
    #pragma unroll
    for (int off = 1; off < 64; off <<= 1) {
        int t = __shfl_up(s, off, 64);
        if (lane >= off) s += t;
    }
    __shared__ int wsum[4];
    if (lane == 63) wsum[wid] = s;
    __syncthreads();
    int wadd = boff[blockIdx.x];
    #pragma unroll
    for (int w = 0; w < 4; w++) if (w < wid) wadd += wsum[w];
    if (i < n) {
        rowptr[i] = wadd + s - v;
        dinv[i]   = rsqrtf((float)c + 1.0f);   // +1 self loop (real degree)
        if (i == n - 1) rowptr[n] = wadd + s;
    }
}

// scatter: write packed {src:16, f16(dinv[src]):16} per padded-CSR slot (4 B/edge).
__global__ void scatter_kernel(const int* __restrict__ src, const int* __restrict__ dst,
                               const int* __restrict__ rowptr, int* __restrict__ cursor,
                               const float* __restrict__ dinv, uint_t* __restrict__ epack, int E) {
    int e = blockIdx.x * blockDim.x + threadIdx.x;
    if (e >= E) return;
    int d = dst[e];
    int s = src[e];
    int p = rowptr[d] + atomicAdd(&cursor[d], 1);
    uint_t hb = (uint_t)__half_as_ushort(__float2half(dinv[s]));
    epack[p] = (uint_t)s | (hb << 16);
}

// ================= bf16 per-node gather aggregation (layer 0 only) ====
template <int C, int MODE>
__global__ __launch_bounds__(256) void node_agg_kernel(
    const ushort_t* __restrict__ h, const int* __restrict__ rowptr,
    const int* __restrict__ degc, const uint_t* __restrict__ epack,
    const float* __restrict__ dinv, const float* __restrict__ bias,
    const int* __restrict__ batch, void* __restrict__ out_v, int n) {
    constexpr int V = C / 64;                 // dwords (2 bf16) per lane per row
    int wave = threadIdx.x >> 6;
    int lane = threadIdx.x & 63;
    int d = blockIdx.x * 4 + wave;
    if (d >= n) return;

    int beg = __builtin_amdgcn_readfirstlane(rowptr[d]);
    int deg = __builtin_amdgcn_readfirstlane(degc[d]);
    const uint_t* hu = (const uint_t*)h;

    float acc[V] = {};
    const uint4* ep4 = (const uint4*)(epack + beg);   // 32 B aligned (beg % 8 == 0)
    uint4 ea, eb, na, nb;
    if (deg > 0) { ea = ep4[0]; eb = ep4[1]; }

    for (int e = 0; e < deg; e += 8) {
        int blk = e >> 3;
        if (e + 8 < deg) { na = ep4[blk * 2 + 2]; nb = ep4[blk * 2 + 3]; }
        uint_t eps[8] = {ea.x, ea.y, ea.z, ea.w, eb.x, eb.y, eb.z, eb.w};
        int   srcs[8];
        float wts[8];
        #pragma unroll
        for (int u = 0; u < 8; u++) {
            bool a = (e + u) < deg;           // wave-uniform
            srcs[u] = a ? (int)(eps[u] & 0xffffu) : d;
            wts[u]  = a ? h16tof(eps[u] >> 16) : 0.0f;
        }
        if constexpr (V == 4) {
            uint_t ra[8], rb[8];
            #pragma unroll
            for (int u = 0; u < 8; u++) {
                const uint_t* row = hu + (size_t)__builtin_amdgcn_readfirstlane(srcs[u]) * (C / 2);
                ra[u] = row[lane];
                rb[u] = row[64 + lane];
            }
            #pragma unroll
            for (int u = 0; u < 8; u++) {
                float w = wts[u];
                acc[0] += w * __uint_as_float(ra[u] << 16);
                acc[1] += w * __uint_as_float(ra[u] & 0xffff0000u);
                acc[2] += w * __uint_as_float(rb[u] << 16);
                acc[3] += w * __uint_as_float(rb[u] & 0xffff0000u);
            }
        } else {
            uint_t rv[8];
            #pragma unroll
            for (int u = 0; u < 8; u++) {
                const uint_t* row = hu + (size_t)__builtin_amdgcn_readfirstlane(srcs[u]) * (C / 2);
                rv[u] = row[lane];
            }
            #pragma unroll
            for (int u = 0; u < 8; u++) {
                float w = wts[u];
                acc[0] += w * __uint_as_float(rv[u] << 16);
                acc[1] += w * __uint_as_float(rv[u] & 0xffff0000u);
            }
        }
        ea = na; eb = nb;
    }

    float dd = dinv[d];
    float self[V];
    {
        const uint_t* row = hu + (size_t)d * (C / 2);
        uint_t sa = row[lane];
        self[0] = __uint_as_float(sa << 16);
        self[1] = __uint_as_float(sa & 0xffff0000u);
        if constexpr (V == 4) {
            uint_t sb = row[64 + lane];
            self[2] = __uint_as_float(sb << 16);
            self[3] = __uint_as_float(sb & 0xffff0000u);
        }
    }

    float r[V];
    if constexpr (MODE >= 1) {
        float2 bA = *(const float2*)(bias + 2 * lane);
        r[0] = fmaxf(dd * acc[0] + dd * dd * self[0] + bA.x, 0.0f);
        r[1] = fmaxf(dd * acc[1] + dd * dd * self[1] + bA.y, 0.0f);
        if constexpr (V == 4) {
            float2 bB = *(const float2*)(bias + 128 + 2 * lane);
            r[2] = fmaxf(dd * acc[2] + dd * dd * self[2] + bB.x, 0.0f);
            r[3] = fmaxf(dd * acc[3] + dd * dd * self[3] + bB.y, 0.0f);
        }
    } else {
        #pragma unroll
        for (int i = 0; i < V; i++)
            r[i] = dd * acc[i] + dd * dd * self[i];
    }

    if constexpr (MODE == 2) {
        float* o = (float*)out_v + (size_t)batch[d] * C;
        atomicAdd(o + 2 * lane, r[0]);
        atomicAdd(o + 2 * lane + 1, r[1]);
        if constexpr (V == 4) {
            atomicAdd(o + 128 + 2 * lane, r[2]);
            atomicAdd(o + 128 + 2 * lane + 1, r[3]);
        }
    } else {
        uint_t* o = (uint_t*)((ushort_t*)out_v + (size_t)d * C);
        __builtin_nontemporal_store((uint_t)f2bf(r[0]) | ((uint_t)f2bf(r[1]) << 16), &o[lane]);
        if constexpr (V == 4)
            __builtin_nontemporal_store((uint_t)f2bf(r[2]) | ((uint_t)f2bf(r[3]) << 16), &o[64 + lane]);
    }
}

// ============ fp8 per-node gather aggregation (layers 1,2; C=256) ============
// READ2=0: one 256 B dword load per row; lane owns channels 4l..4l+3.
// READ2=1: two 128 B ushort loads per row (2x the in-flight requests);
//          lane owns channels {2l,2l+1,128+2l,128+2l+1} (round-2 mapping).
// MODE 1: out bf16 = relu(dd*sum + dd^2*self + bias)
// MODE 2: atomicAdd relu(...) into fp32 out[batch[d]]
template <int MODE, int READ2>
__global__ __launch_bounds__(256) void node_agg_fp8_kernel(
    const uchar_t* __restrict__ h8, const int* __restrict__ rowptr,
    const int* __restrict__ degc, const uint_t* __restrict__ epack,
    const float* __restrict__ dinv, const float* __restrict__ bias,
    const int* __restrict__ batch, void* __restrict__ out_v, int n) {
    int wave = threadIdx.x >> 6;
    int lane = threadIdx.x & 63;
    int d = blockIdx.x * 4 + wave;
    if (d >= n) return;

    int beg = __builtin_amdgcn_readfirstlane(rowptr[d]);
    int deg = __builtin_amdgcn_readfirstlane(degc[d]);

    float a0 = 0.0f, a1 = 0.0f, a2 = 0.0f, a3 = 0.0f;
    const uint4* ep4 = (const uint4*)(epack + beg);
    uint4 ea, eb, na, nb;
    if (deg > 0) { ea = ep4[0]; eb = ep4[1]; }

    for (int e = 0; e < deg; e += 8) {
        int blk = e >> 3;
        if (e + 8 < deg) { na = ep4[blk * 2 + 2]; nb = ep4[blk * 2 + 3]; }
        uint_t eps[8] = {ea.x, ea.y, ea.z, ea.w, eb.x, eb.y, eb.z, eb.w};
        int   srcs[8];
        float wts[8];
        #pragma unroll
        for (int u = 0; u < 8; u++) {
            bool a = (e + u) < deg;           // wave-uniform
            srcs[u] = a ? (int)(eps[u] & 0xffffu) : d;
            wts[u]  = a ? h16tof(eps[u] >> 16) : 0.0f;
        }
        if constexpr (READ2) {
            uint_t ra[8], rb[8];
            #pragma unroll
            for (int u = 0; u < 8; u++) {
                const ushort_t* row = (const ushort_t*)h8 + (size_t)__builtin_amdgcn_readfirstlane(srcs[u]) * 128;
                ra[u] = row[lane];            // bytes 2l,2l+1  -> ch 2l,2l+1
                rb[u] = row[64 + lane];       // bytes 128+2l.. -> ch 128+2l,128+2l+1
            }
            #pragma unroll
            for (int u = 0; u < 8; u++) {
                float w = wts[u];
                f32x2_t lo = __builtin_amdgcn_cvt_pk_f32_fp8(ra[u], false);
                f32x2_t hi = __builtin_amdgcn_cvt_pk_f32_fp8(rb[u], false);
                a0 += w * lo.x;
                a1 += w * lo.y;
                a2 += w * hi.x;
                a3 += w * hi.y;
            }
        } else {
            const uint_t* hu = (const uint_t*)h8;
            uint_t rv[8];
            #pragma unroll
            for (int u = 0; u < 8; u++)
                rv[u] = hu[(size_t)__builtin_amdgcn_readfirstlane(srcs[u]) * 64 + lane];
            #pragma unroll
            for (int u = 0; u < 8; u++) {
                float w = wts[u];
                f32x2_t lo = __builtin_amdgcn_cvt_pk_f32_fp8(rv[u], false);
                f32x2_t hi = __builtin_amdgcn_cvt_pk_f32_fp8(rv[u], true);
                a0 += w * lo.x;
                a1 += w * lo.y;
                a2 += w * hi.x;
                a3 += w * hi.y;
            }
        }
        ea = na; eb = nb;
    }

    float dd = dinv[d];
    float dd2 = dd * dd;

    if constexpr (READ2) {
        const ushort_t* srow = (const ushort_t*)h8 + (size_t)d * 128;
        f32x2_t slo = __builtin_amdgcn_cvt_pk_f32_fp8((uint_t)srow[lane], false);
        f32x2_t shi = __builtin_amdgcn_cvt_pk_f32_fp8((uint_t)srow[64 + lane], false);
        float2 bA = *(const float2*)(bias + 2 * lane);
        float2 bB = *(const float2*)(bias + 128 + 2 * lane);
        float r0 = fmaxf(dd * a0 + dd2 * slo.x + bA.x, 0.0f);
        float r1 = fmaxf(dd * a1 + dd2 * slo.y + bA.y, 0.0f);
        float r2 = fmaxf(dd * a2 + dd2 * shi.x + bB.x, 0.0f);
        float r3 = fmaxf(dd * a3 + dd2 * shi.y + bB.y, 0.0f);
        if constexpr (MODE == 2) {
            float* o = (float*)out_v + (size_t)batch[d] * CH;
            atomicAdd(o + 2 * lane, r0);
            atomicAdd(o + 2 * lane + 1, r1);
            atomicAdd(o + 128 + 2 * lane, r2);
            atomicAdd(o + 128 + 2 * lane + 1, r3);
        } else {
            uint_t* o = (uint_t*)((ushort_t*)out_v + (size_t)d * CH);
            o[lane]      = (uint_t)f2bf(r0) | ((uint_t)f2bf(r1) << 16);
            o[64 + lane] = (uint_t)f2bf(r2) | ((uint_t)f2bf(r3) << 16);
        }
    } else {
        const uint_t* hu = (const uint_t*)h8;
        uint_t sv = hu[(size_t)d * 64 + lane];
        f32x2_t slo = __builtin_amdgcn_cvt_pk_f32_fp8(sv, false);
        f32x2_t shi = __builtin_amdgcn_cvt_pk_f32_fp8(sv, true);
        float4 b4 = *(const float4*)(bias + 4 * lane);
        float r0 = fmaxf(dd * a0 + dd2 * slo.x + b4.x, 0.0f);
        float r1 = fmaxf(dd * a1 + dd2 * slo.y + b4.y, 0.0f);
        float r2 = fmaxf(dd * a2 + dd2 * shi.x + b4.z, 0.0f);
        float r3 = fmaxf(dd * a3 + dd2 * shi.y + b4.w, 0.0f);
        if constexpr (MODE == 2) {
            float* o = (float*)out_v + (size_t)batch[d] * CH + 4 * lane;
            atomicAdd(o + 0, r0);
            atomicAdd(o + 1, r1);
            atomicAdd(o + 2, r2);
            atomicAdd(o + 3, r3);
        } else {
            u32x2_t st;
            st.x = (uint_t)f2bf(r0) | ((uint_t)f2bf(r1) << 16);
            st.y = (uint_t)f2bf(r2) | ((uint_t)f2bf(r3) << 16);
            *((u32x2_t*)((ushort_t*)out_v + (size_t)d * CH) + lane) = st;
        }
    }
}

// ================= bf16 MFMA GEMM: C[M,256] = A[M,K] @ Wt[N,K]^T =================
// F8OUT=1: stage fp8 e4m3 tile in LDS, copy out with uint4 stores (full sectors —
// byte-granular global stores caused write-allocate RMW storms in round 4).
typedef __attribute__((ext_vector_type(8))) short bf16x8;
typedef __attribute__((ext_vector_type(4))) float f32x4;

template <int MODE, int F8OUT>
__global__ __launch_bounds__(256) void gemm_bf16_kernel(
    const ushort_t* __restrict__ A, const ushort_t* __restrict__ Wt,
    const float* __restrict__ bias, void* __restrict__ Cv, int M, int K) {
    __shared__ union alignas(16) {
        ushort_t ab[2][128][40];
        uchar_t  f8[128][128];
    } smem;
    int tid = threadIdx.x;
    int row0 = blockIdx.x * 128, col0 = blockIdx.y * 128;
    int lr = tid >> 2, lq = tid & 3;
    int lane = tid & 63, wv = tid >> 6;
    int wr = (wv >> 1) * 64, wc = (wv & 1) * 64;
    int r16 = lane & 15, quad = lane >> 4;

    f32x4 acc[4][4] = {};

    for (int k0 = 0; k0 < K; k0 += 32) {
        {
            int gr0 = row0 + lr, gr1 = row0 + lr + 64;
            uint4 a0 = make_uint4(0, 0, 0, 0), a1 = make_uint4(0, 0, 0, 0);
            if (gr0 < M) a0 = *(const uint4*)(A + (size_t)gr0 * K + k0 + lq * 8);
            if (gr1 < M) a1 = *(const uint4*)(A + (size_t)gr1 * K + k0 + lq * 8);
            *(uint4*)&smem.ab[0][lr][lq * 8]      = a0;
            *(uint4*)&smem.ab[0][lr + 64][lq * 8] = a1;
            uint4 b0 = *(const uint4*)(Wt + (size_t)(col0 + lr) * K + k0 + lq * 8);
            uint4 b1 = *(const uint4*)(Wt + (size_t)(col0 + lr + 64) * K + k0 + lq * 8);
            *(uint4*)&smem.ab[1][lr][lq * 8]      = b0;
            *(uint4*)&smem.ab[1][lr + 64][lq * 8] = b1;
        }
        __syncthreads();
        bf16x8 af[4], bfr[4];
        #pragma unroll
        for (int i = 0; i < 4; i++) af[i]  = *(const bf16x8*)&smem.ab[0][wr + i * 16 + r16][quad * 8];
        #pragma unroll
        for (int j = 0; j < 4; j++) bfr[j] = *(const bf16x8*)&smem.ab[1][wc + j * 16 + r16][quad * 8];
        #pragma unroll
        for (int i = 0; i < 4; i++)
            #pragma unroll
            for (int j = 0; j < 4; j++)
                acc[i][j] = __builtin_amdgcn_mfma_f32_16x16x32_bf16(af[i], bfr[j], acc[i][j], 0, 0, 0);
        __syncthreads();
    }

    if constexpr (F8OUT) {
        // stage fp8 bytes in LDS (tile-local cols 0..127)
        #pragma unroll
        for (int j = 0; j < 4; j++) {
            int colt = wc + j * 16 + r16;
            #pragma unroll
            for (int i = 0; i < 4; i++) {
                #pragma unroll
                for (int r = 0; r < 4; r++) {
                    float v = acc[i][j][r];
                    uint_t pk = __builtin_amdgcn_cvt_pk_fp8_f32(v, v, 0u, false);
                    smem.f8[wr + i * 16 + quad * 4 + r][colt] = (uchar_t)(pk & 0xffu);
                }
            }
        }
        __syncthreads();
        // vectorized copy-out: 128 rows x 128 B, uint4 per thread x4
        uchar_t* C8 = (uchar_t*)Cv;
        #pragma unroll
        for (int k = 0; k < 4; k++) {
            int idx = k * 256 + tid;          // 0..1023
            int r = idx >> 3, coff = (idx & 7) * 16;
            if (row0 + r < M)
                *(uint4*)(C8 + (size_t)(row0 + r) * 256 + col0 + coff) =
                    *(const uint4*)&smem.f8[r][coff];
        }
    } else {
        #pragma unroll
        for (int j = 0; j < 4; j++) {
            int colc = col0 + wc + j * 16 + r16;
            float bval = (MODE == 1) ? bias[colc] : 0.0f;
            #pragma unroll
            for (int i = 0; i < 4; i++) {
                #pragma unroll
                for (int r = 0; r < 4; r++) {
                    int row = row0 + wr + i * 16 + quad * 4 + r;
                    if (row < M) {
                        float v = acc[i][j][r];
                        if (MODE == 1) v = fmaxf(v + bval, 0.0f);
                        ((ushort_t*)Cv)[(size_t)row * 256 + colc] = f2bf(v);
                    }
                }
            }
        }
    }
}

extern "C" void kernel_launch(void* const* d_in, const int* in_sizes, int n_in,
                              void* d_out, int out_size, void* d_ws, size_t ws_size,
                              hipStream_t stream) {
    const float* x   = (const float*)d_in[0];
    const float* W0  = (const float*)d_in[1];
    const float* b0  = (const float*)d_in[2];
    const float* W1  = (const float*)d_in[3];
    const float* b1  = (const float*)d_in[4];
    const float* W2  = (const float*)d_in[5];
    const float* b2  = (const float*)d_in[6];
    const int*   ei  = (const int*)d_in[7];
    const int*   src = ei;
    const int*   dst = ei + NE;
    const int*   batch = (const int*)d_in[8];
    float* out = (float*)d_out;

    char* ws = (char*)d_ws;
    ushort_t* P1  = (ushort_t*)ws;                        // [NN,256] bf16 (h1, then h2) 25.6 MB
    ushort_t* G0  = (ushort_t*)(ws + 25600000ull);        // [NN,128] bf16 (agg0 out)    12.8 MB
    uchar_t*  F8  = (uchar_t*) (ws + 38400000ull);        // [NN,256] fp8 (t1, then t2)  12.8 MB
    ushort_t* xbf = (ushort_t*)(ws + 51200000ull);        // [NN,128] bf16               12.8 MB
    ushort_t* W0t = (ushort_t*)(ws + 64000000ull);        // [256,128] bf16
    ushort_t* W1t = (ushort_t*)(ws + 64065536ull);        // [256,256] bf16
    ushort_t* W2t = (ushort_t*)(ws + 64196608ull);        // [256,256] bf16
    float*    dinv   = (float*)(ws + 64327680ull);        // [NN]
    int*      rowptr = (int*)  (ws + 64527680ull);        // [NN+1]
    int*      cnt    = (int*)  (ws + 64727808ull);        // [NN] real degrees (kept)
    uint_t*   epack  = (uint_t*)(ws + 64927808ull);       // padded CSR, <= 4.8 MB
    int*      bsum   = (int*)  (ws + 71327808ull);        // [<=256]
    int*      cursor = (int*)ws;                          // aliases P1 (free until GEMM0)

    const int scanBlocks = (NN + 255) / 256;              // 196
    const int nodeBlocks = (NN + 3) / 4;                  // 1 node per wave, 4 waves/block
    const dim3 ggrid((NN + 127) / 128, 2);

    // --- prep converts ---
    conv_x_kernel<<<(NN * CIN / 4 + 255) / 256, 256, 0, stream>>>((const float4*)x, (ushort4*)xbf, NN * CIN / 4);
    conv_wt3_kernel<<<640, 256, 0, stream>>>(W0, W1, W2, W0t, W1t, W2t);

    // --- CSR + normalization (8-aligned padded rows) ---
    hipMemsetAsync(cnt, 0, (size_t)NN * 4, stream);
    count_kernel<<<(NE + 255) / 256, 256, 0, stream>>>(dst, cnt, NE);
    scan_bsum_kernel<<<scanBlocks, 256, 0, stream>>>(cnt, bsum, NN);
    scan_boff_kernel<<<1, 256, 0, stream>>>(bsum, scanBlocks);
    scan_final_kernel<<<scanBlocks, 256, 0, stream>>>(cnt, bsum, rowptr, dinv, NN);
    hipMemsetAsync(cursor, 0, (size_t)NN * 4, stream);
    scatter_kernel<<<(NE + 255) / 256, 256, 0, stream>>>(src, dst, rowptr, cursor, dinv, epack, NE);

    // --- layer 0: agg x (bf16, C=128), GEMM0 fused bias+relu -> h1 (bf16) ---
    node_agg_kernel<CIN, 0><<<nodeBlocks, 256, 0, stream>>>(xbf, rowptr, cnt, epack, dinv, nullptr, nullptr, G0, NN);
    gemm_bf16_kernel<1, 0><<<ggrid, 256, 0, stream>>>(G0, W0t, b0, P1, NN, CIN);

    // --- layer 1: t1 = h1@W1 (fp8 out via LDS repack), agg fp8 READ1 -> h2 ---
    gemm_bf16_kernel<0, 1><<<ggrid, 256, 0, stream>>>(P1, W1t, nullptr, F8, NN, CH);
    node_agg_fp8_kernel<1, 0><<<nodeBlocks, 256, 0, stream>>>(F8, rowptr, cnt, epack, dinv, b1, nullptr, P1, NN);

    // --- layer 2: t2 = h2@W2 (fp8 out via LDS repack), agg fp8 READ2 + pool ---
    gemm_bf16_kernel<0, 1><<<ggrid, 256, 0, stream>>>(P1, W2t, nullptr, F8, NN, CH);
    hipMemsetAsync(out, 0, (size_t)NG * CH * 4, stream);
    node_agg_fp8_kernel<2, 1><<<nodeBlocks, 256, 0, stream>>>(F8, rowptr, cnt, epack, dinv, b2, batch, out, NN);
}